// Round 7
// baseline (743.372 us; speedup 1.0000x reference)
//
#include <hip/hip_runtime.h>
#include <hip/hip_bf16.h>

#define B_    8
#define S_    2048
#define HID_  512
#define H_    8
#define D_    64
#define FF_   2048
#define QKVB_ 1544   // H*(3*D+1) = 8*193
#define NCH_  32     // S/64 chunks

typedef unsigned short u16;
typedef __attribute__((ext_vector_type(8))) short short8;
typedef __attribute__((ext_vector_type(4))) float f32x4;

__device__ __forceinline__ u16 f2bf(float x) {           // RNE fp32->bf16
  unsigned u = __builtin_bit_cast(unsigned, x);
  unsigned r = (u + 0x7FFFu + ((u >> 16) & 1u)) >> 16;
  return (u16)r;
}
__device__ __forceinline__ float bf2f(u16 v) {
  return __builtin_bit_cast(float, (unsigned)v << 16);
}
__device__ __forceinline__ void gload16(const void* g, void* l) {
  __builtin_amdgcn_global_load_lds(
      (const __attribute__((address_space(1))) unsigned int*)g,
      (__attribute__((address_space(3))) unsigned int*)l, 16, 0, 0);
}

// 64x64x64 product C[r][c] = sum_k F[r][k]*G[c][k], bf16 LDS operands.
template<int FS, int GS>
__device__ __forceinline__ void prod64(const u16* __restrict__ F,
                                       const u16* __restrict__ G,
                                       int wrow0, int lane, f32x4 acc[4])
{
  short8 f0 = *(const short8*)&F[(wrow0 + (lane & 15)) * FS + ((lane >> 4) * 8)];
  short8 f1 = *(const short8*)&F[(wrow0 + (lane & 15)) * FS + 32 + ((lane >> 4) * 8)];
  #pragma unroll
  for (int c0 = 0; c0 < 4; ++c0) {
    short8 g0 = *(const short8*)&G[(c0 * 16 + (lane & 15)) * GS + ((lane >> 4) * 8)];
    short8 g1 = *(const short8*)&G[(c0 * 16 + (lane & 15)) * GS + 32 + ((lane >> 4) * 8)];
    acc[c0] = __builtin_amdgcn_mfma_f32_16x16x32_bf16(f0, g0, acc[c0], 0, 0, 0);
    acc[c0] = __builtin_amdgcn_mfma_f32_16x16x32_bf16(f1, g1, acc[c0], 0, 0, 0);
  }
}

// ---------------------------------------------------------------------------
// bf16 GEMM with global_load_lds staging + both-sides swizzle. TRANS writes
// the output [S,B]->[B,S]-transposed (fuses the final transpose pass).
// ---------------------------------------------------------------------------
template<bool BIAS, bool RELU, bool RES, bool OUTBF, bool TRANS>
__global__ __launch_bounds__(256) void gemm_bf(
    const u16* __restrict__ A, const u16* __restrict__ W,
    const float* __restrict__ bias, const float* __restrict__ res,
    void* __restrict__ Cout, int M, int N, int K)
{
  __shared__ __align__(16) u16 As[128 * 64];
  __shared__ __align__(16) u16 Bs[128 * 64];
  const int tid = threadIdx.x, lane = tid & 63, wv = tid >> 6;
  const int bm = blockIdx.y * 128, bn = blockIdx.x * 128;
  const int wr = wv >> 1, wc = wv & 1;
  const int row16 = lane & 15, kg = lane >> 4;
  const int srow = lane >> 3;
  const int soff = ((lane & 7) * 16) ^ (srow << 4);

  f32x4 acc[4][4] = {};
  const int ktiles = K >> 6;

  for (int kt = 0; kt < ktiles; ++kt) {
    #pragma unroll
    for (int i = 0; i < 4; ++i) {
      const int r = i * 32 + wv * 8;
      const char* ga = (const char*)(A + (size_t)(bm + r + srow) * K + (size_t)kt * 64) + soff;
      gload16(ga, &As[r * 64]);
      const char* gw = (const char*)(W + (size_t)(bn + r + srow) * K + (size_t)kt * 64) + soff;
      gload16(gw, &Bs[r * 64]);
    }
    __syncthreads();

    #pragma unroll
    for (int kh = 0; kh < 2; ++kh) {
      const int fb = ((kh * 64 + kg * 16) ^ ((row16 & 7) << 4)) >> 1;
      short8 af[4], bf_[4];
      #pragma unroll
      for (int m = 0; m < 4; ++m)
        af[m] = *(const short8*)&As[(wr * 64 + m * 16 + row16) * 64 + fb];
      #pragma unroll
      for (int n = 0; n < 4; ++n)
        bf_[n] = *(const short8*)&Bs[(wc * 64 + n * 16 + row16) * 64 + fb];
      #pragma unroll
      for (int m = 0; m < 4; ++m)
        #pragma unroll
        for (int n = 0; n < 4; ++n)
          acc[m][n] = __builtin_amdgcn_mfma_f32_16x16x32_bf16(af[m], bf_[n], acc[m][n], 0, 0, 0);
    }
    __syncthreads();
  }

  #pragma unroll
  for (int m = 0; m < 4; ++m) {
    #pragma unroll
    for (int n = 0; n < 4; ++n) {
      const int gcol = bn + wc * 64 + n * 16 + row16;
      if (gcol < N) {
        #pragma unroll
        for (int j = 0; j < 4; ++j) {
          const int grow = bm + wr * 64 + m * 16 + kg * 4 + j;
          float v = acc[m][n][j];
          if (BIAS) v += bias[gcol];
          if (RES)  v += res[(size_t)grow * N + gcol];
          if (RELU) v = fmaxf(v, 0.f);
          size_t di;
          if (TRANS) di = ((size_t)(grow & 7) * S_ + (grow >> 3)) * N + gcol;
          else       di = (size_t)grow * N + gcol;
          if (OUTBF) ((u16*)Cout)[di] = f2bf(v);
          else       ((float*)Cout)[di] = v;
        }
      }
    }
  }
}

// ---------------------------------------------------------------------------
__global__ __launch_bounds__(256) void conv_w(const float* __restrict__ s,
                                              u16* __restrict__ d, int n, int npad)
{
  int i = blockIdx.x * 256 + threadIdx.x;
  if (i < npad) d[i] = (i < n) ? f2bf(s[i]) : (u16)0;
}

__global__ __launch_bounds__(64) void conv_x(const float* __restrict__ x,
                                             u16* __restrict__ xbf)
{
  size_t m = blockIdx.x;
  size_t s = m >> 3, b = m & 7;
  const float4* src = (const float4*)(x + (b * (size_t)S_ + s) * HID_);
  float4 v0 = src[threadIdx.x], v1 = src[64 + threadIdx.x];
  u16* dst = xbf + m * HID_;
  uint2 p0, p1;
  p0.x = (unsigned)f2bf(v0.x) | ((unsigned)f2bf(v0.y) << 16);
  p0.y = (unsigned)f2bf(v0.z) | ((unsigned)f2bf(v0.w) << 16);
  p1.x = (unsigned)f2bf(v1.x) | ((unsigned)f2bf(v1.y) << 16);
  p1.y = (unsigned)f2bf(v1.z) | ((unsigned)f2bf(v1.w) << 16);
  *(uint2*)&dst[threadIdx.x * 4] = p0;
  *(uint2*)&dst[256 + threadIdx.x * 4] = p1;
}

__global__ __launch_bounds__(64) void ln_bf(const float* __restrict__ x,
    const float* __restrict__ g, const float* __restrict__ bt,
    u16* __restrict__ o)
{
  size_t row = blockIdx.x;
  int lane = threadIdx.x;
  const float4* xr = (const float4*)(x + row * HID_);
  float4 v0 = xr[lane];
  float4 v1 = xr[64 + lane];
  float s  = v0.x + v0.y + v0.z + v0.w + v1.x + v1.y + v1.z + v1.w;
  float ss = v0.x*v0.x + v0.y*v0.y + v0.z*v0.z + v0.w*v0.w
           + v1.x*v1.x + v1.y*v1.y + v1.z*v1.z + v1.w*v1.w;
  #pragma unroll
  for (int off = 32; off; off >>= 1) {
    s  += __shfl_xor(s, off);
    ss += __shfl_xor(ss, off);
  }
  float mean = s * (1.f / HID_);
  float inv  = rsqrtf(ss * (1.f / HID_) - mean * mean + 1e-5f);
  const float4* gv = (const float4*)g;
  const float4* bv = (const float4*)bt;
  float4 g0 = gv[lane], g1 = gv[64 + lane];
  float4 b0 = bv[lane], b1 = bv[64 + lane];
  uint2 p0, p1;
  p0.x = (unsigned)f2bf((v0.x - mean) * inv * g0.x + b0.x)
       | ((unsigned)f2bf((v0.y - mean) * inv * g0.y + b0.y) << 16);
  p0.y = (unsigned)f2bf((v0.z - mean) * inv * g0.z + b0.z)
       | ((unsigned)f2bf((v0.w - mean) * inv * g0.w + b0.w) << 16);
  p1.x = (unsigned)f2bf((v1.x - mean) * inv * g1.x + b1.x)
       | ((unsigned)f2bf((v1.y - mean) * inv * g1.y + b1.y) << 16);
  p1.y = (unsigned)f2bf((v1.z - mean) * inv * g1.z + b1.z)
       | ((unsigned)f2bf((v1.w - mean) * inv * g1.w + b1.w) << 16);
  u16* ov = o + row * HID_;
  *(uint2*)&ov[lane * 4] = p0;
  *(uint2*)&ov[256 + lane * 4] = p1;
}

// ---------------------------------------------------------------------------
// Delta rule 3-phase. p1 now: fused softmax/sigmoid staging, A via MFMA,
// T=(I+A)^-1 via blocked inversion (4 parallel 16x16 diag inversions + 6
// off-diag 16^3 fp32 matmuls with a per-wave dependency chain), then
// CK/U0/M/N all via MFMA.  beta is folded into T's columns (T' = T diag(beta)).
// ---------------------------------------------------------------------------
__device__ __forceinline__ void diag_inv(int w, const u16* Am, float* Tm, int lane)
{
  if (lane < 16) {
    const int c = lane;
    float t[16];
    #pragma unroll
    for (int i = 0; i < 16; ++i) t[i] = (i == c) ? 1.f : 0.f;
    #pragma unroll
    for (int i = 1; i < 16; ++i) {
      float ti = t[i];
      #pragma unroll
      for (int j = 0; j < 16; ++j)
        if (j < i) ti = fmaf(-bf2f(Am[(w * 16 + i) * 72 + w * 16 + j]), t[j], ti);
      t[i] = ti;
    }
    #pragma unroll
    for (int r = 0; r < 16; ++r) Tm[(w * 16 + r) * 65 + w * 16 + c] = t[r];
  }
}

__device__ __forceinline__ void off_block(int bi, int bj, const u16* Am,
                                          float* Tm, int lane)
{
  const int c = lane & 15, rq = lane >> 4;
  float x[4] = {};
  for (int k = bj; k < bi; ++k) {
    #pragma unroll
    for (int s = 0; s < 16; ++s) {
      float ts = Tm[(k * 16 + s) * 65 + bj * 16 + c];
      #pragma unroll
      for (int r4 = 0; r4 < 4; ++r4)
        x[r4] = fmaf(bf2f(Am[(bi * 16 + rq * 4 + r4) * 72 + k * 16 + s]), ts, x[r4]);
    }
  }
  float acc[4] = {};
  #pragma unroll
  for (int s = 0; s < 16; ++s) {
    float xs = __shfl(x[s & 3], (s >> 2) * 16 + c);
    #pragma unroll
    for (int r4 = 0; r4 < 4; ++r4)
      acc[r4] = fmaf(Tm[(bi * 16 + rq * 4 + r4) * 65 + bi * 16 + s], xs, acc[r4]);
  }
  #pragma unroll
  for (int r4 = 0; r4 < 4; ++r4)
    Tm[(bi * 16 + rq * 4 + r4) * 65 + bj * 16 + c] = -acc[r4];
}

__global__ __launch_bounds__(256, 2) void delta_p1(const float* __restrict__ qkvb,
                                                   u16* __restrict__ MTg,
                                                   u16* __restrict__ Ng,
                                                   u16* __restrict__ CKg,
                                                   u16* __restrict__ U0Tg)
{
  __shared__ __align__(16) u16 Kb[64 * 72];
  __shared__ __align__(16) u16 KTb[64 * 72];
  __shared__ __align__(16) u16 VTb[64 * 72];
  __shared__ __align__(16) u16 Am[64 * 72];
  __shared__ __align__(16) u16 Tb[64 * 72];
  __shared__ __align__(16) u16 CKTb[64 * 72];
  __shared__ __align__(16) u16 U0Tb[64 * 72];
  __shared__ float Tm[64][65];
  __shared__ float bet[64];

  const int id5 = blockIdx.x, bh = id5 >> 5;
  const int b = bh & 7, h = bh >> 3, t0 = (id5 & 31) * 64;
  const int tid = threadIdx.x, lane = tid & 63, wv = tid >> 6;
  const int wrow0 = wv * 16;
  const size_t hoff = (size_t)h * 193;
  const size_t mb = (size_t)id5 * 4096;

  if (tid < 64) {
    float bb = qkvb[((size_t)(t0 + tid) * B_ + b) * QKVB_ + hoff + 192];
    bet[tid] = 1.f / (1.f + __expf(-bb));
  }
  for (int i = 0; i < 16; ++i) {
    int row = i * 4 + wv;
    size_t gb = ((size_t)(t0 + row) * B_ + b) * QKVB_ + hoff;
    float k = qkvb[gb + 64 + lane];
    float v = qkvb[gb + 128 + lane];
    float mk = k;
    #pragma unroll
    for (int off = 32; off; off >>= 1) mk = fmaxf(mk, __shfl_xor(mk, off));
    float ek = __expf(k - mk), sk = ek;
    #pragma unroll
    for (int off = 32; off; off >>= 1) sk += __shfl_xor(sk, off);
    u16 kb = f2bf(ek / sk);
    Kb[row * 72 + lane] = kb;
    KTb[lane * 72 + row] = kb;
    VTb[lane * 72 + row] = f2bf(v);
  }
  __syncthreads();

  // A = beta ⊙ K K^T (MFMA), bf16 in Am
  {
    f32x4 a[4] = {};
    prod64<72, 72>(Kb, Kb, wrow0, lane, a);
    #pragma unroll
    for (int c0 = 0; c0 < 4; ++c0)
      #pragma unroll
      for (int j = 0; j < 4; ++j) {
        int row = wrow0 + (lane >> 4) * 4 + j, col = c0 * 16 + (lane & 15);
        Am[row * 72 + col] = f2bf(bet[row] * a[c0][j]);
      }
  }
  __syncthreads();

  diag_inv(wv, Am, &Tm[0][0], lane);
  __syncthreads();
  // level 1
  if (wv == 1) off_block(1, 0, Am, &Tm[0][0], lane);
  else if (wv == 2) off_block(2, 1, Am, &Tm[0][0], lane);
  else if (wv == 3) off_block(3, 2, Am, &Tm[0][0], lane);
  __syncthreads();
  // level 2
  if (wv == 1) off_block(2, 0, Am, &Tm[0][0], lane);
  else if (wv == 2) off_block(3, 1, Am, &Tm[0][0], lane);
  __syncthreads();
  // level 3
  if (wv == 1) off_block(3, 0, Am, &Tm[0][0], lane);
  __syncthreads();

  // T' = T * diag(beta), bf16
  for (int idx = tid; idx < 4096; idx += 256) {
    int r = idx >> 6, cc = idx & 63;
    Tb[r * 72 + cc] = (cc <= r) ? f2bf(Tm[r][cc] * bet[cc]) : (u16)0;
  }
  __syncthreads();

  // CK = T' K, U0 = T' V (MFMA); write CKg row-major, CKTb/U0Tb transposed
  {
    f32x4 ck[4] = {}, u0[4] = {};
    prod64<72, 72>(Tb, KTb, wrow0, lane, ck);
    prod64<72, 72>(Tb, VTb, wrow0, lane, u0);
    #pragma unroll
    for (int c0 = 0; c0 < 4; ++c0) {
      union { u16 u[4]; uint2 v; } pk, pu;
      #pragma unroll
      for (int j = 0; j < 4; ++j) {
        int row = wrow0 + (lane >> 4) * 4 + j, col = c0 * 16 + (lane & 15);
        u16 c = f2bf(ck[c0][j]);
        CKg[mb + (size_t)row * 64 + col] = c;
        pk.u[j] = c;
        pu.u[j] = f2bf(u0[c0][j]);
      }
      int tcol = c0 * 16 + (lane & 15), trow = wrow0 + (lane >> 4) * 4;
      *(uint2*)&CKTb[tcol * 72 + trow] = pk.v;
      *(uint2*)&U0Tb[tcol * 72 + trow] = pu.v;
    }
  }
  __syncthreads();

  // MT = K^T CK, N = U0^T K (MFMA) -> global; U0Tg coalesced copy
  {
    f32x4 mt[4] = {}, nn[4] = {};
    prod64<72, 72>(KTb, CKTb, wrow0, lane, mt);
    prod64<72, 72>(U0Tb, KTb, wrow0, lane, nn);
    #pragma unroll
    for (int c0 = 0; c0 < 4; ++c0)
      #pragma unroll
      for (int j = 0; j < 4; ++j) {
        int row = wrow0 + (lane >> 4) * 4 + j, col = c0 * 16 + (lane & 15);
        MTg[mb + (size_t)row * 64 + col] = f2bf(mt[c0][j]);
        Ng[mb + (size_t)row * 64 + col]  = f2bf(nn[c0][j]);
      }
    int prow = tid >> 2, pc0 = (tid & 3) * 16;
    short8 a0 = *(const short8*)&U0Tb[prow * 72 + pc0];
    short8 a1 = *(const short8*)&U0Tb[prow * 72 + pc0 + 8];
    *(uint4*)&U0Tg[mb + prow * 64 + pc0]     = __builtin_bit_cast(uint4, a0);
    *(uint4*)&U0Tg[mb + prow * 64 + pc0 + 8] = __builtin_bit_cast(uint4, a1);
  }
}

__global__ __launch_bounds__(256, 1) void delta_p2(const u16* __restrict__ MTg,
                                                   const u16* __restrict__ Ng,
                                                   float* __restrict__ qkvb)
{
  __shared__ float Ws[64][65];
  __shared__ __align__(16) u16 Wbf[64 * 72];
  __shared__ __align__(16) u16 MTb[64 * 72];
  __shared__ __align__(16) u16 Nb[64 * 72];
  const int bh = blockIdx.x, b = bh & 7, h = bh >> 3;
  const int tid = threadIdx.x, lane = tid & 63, wv = tid >> 6, wrow0 = wv * 16;
  const size_t hoff = (size_t)h * 193;
  const int prow = tid >> 2, pc0 = (tid & 3) * 16;

  for (int i = tid; i < 64 * 65; i += 256) (&Ws[0][0])[i] = 0.f;
  for (int i = tid; i < 64 * 72; i += 256) Wbf[i] = 0;
  __syncthreads();

  size_t base = (size_t)bh * NCH_ * 4096;
  uint4 rm0 = *(const uint4*)&MTg[base + prow * 64 + pc0];
  uint4 rm1 = *(const uint4*)&MTg[base + prow * 64 + pc0 + 8];
  uint4 rn0 = *(const uint4*)&Ng[base + prow * 64 + pc0];
  uint4 rn1 = *(const uint4*)&Ng[base + prow * 64 + pc0 + 8];

  for (int j = 0; j < NCH_; ++j) {
    *(short8*)&MTb[prow * 72 + pc0]     = __builtin_bit_cast(short8, rm0);
    *(short8*)&MTb[prow * 72 + pc0 + 8] = __builtin_bit_cast(short8, rm1);
    *(short8*)&Nb[prow * 72 + pc0]      = __builtin_bit_cast(short8, rn0);
    *(short8*)&Nb[prow * 72 + pc0 + 8]  = __builtin_bit_cast(short8, rn1);
    {
      const int t0 = j * 64;
      #pragma unroll
      for (int i = 0; i < 16; ++i)
        qkvb[((size_t)(t0 + prow) * B_ + b) * QKVB_ + hoff + 128 + pc0 + i] = Ws[prow][pc0 + i];
    }
    if (j + 1 < NCH_) {   // prefetch next chunk (lands during compute)
      size_t nb2 = base + (size_t)(j + 1) * 4096;
      rm0 = *(const uint4*)&MTg[nb2 + prow * 64 + pc0];
      rm1 = *(const uint4*)&MTg[nb2 + prow * 64 + pc0 + 8];
      rn0 = *(const uint4*)&Ng[nb2 + prow * 64 + pc0];
      rn1 = *(const uint4*)&Ng[nb2 + prow * 64 + pc0 + 8];
    }
    __syncthreads();
    f32x4 a[4] = {};
    prod64<72, 72>(Wbf, MTb, wrow0, lane, a);
    #pragma unroll
    for (int c0 = 0; c0 < 4; ++c0)
      #pragma unroll
      for (int jj = 0; jj < 4; ++jj) {
        int row = wrow0 + (lane >> 4) * 4 + jj, col = c0 * 16 + (lane & 15);
        float w = Ws[row][col] + bf2f(Nb[row * 72 + col]) - a[c0][jj];
        Ws[row][col] = w;
        Wbf[row * 72 + col] = f2bf(w);
      }
    __syncthreads();
  }
}

__global__ __launch_bounds__(256, 2) void delta_p3(const float* __restrict__ qkvb,
                                                   const u16* __restrict__ CKg,
                                                   const u16* __restrict__ U0Tg,
                                                   u16* __restrict__ attnb)
{
  __shared__ __align__(16) u16 Qb[64 * 72];
  __shared__ __align__(16) u16 Kb[64 * 72];
  __shared__ __align__(16) u16 W0b[64 * 72];
  __shared__ __align__(16) u16 CKb[64 * 72];
  __shared__ __align__(16) u16 U0Tb[64 * 72];
  __shared__ __align__(16) u16 Gb[64 * 72];
  __shared__ __align__(16) u16 UTb[64 * 72];

  const int id5 = blockIdx.x, bh = id5 >> 5;
  const int b = bh & 7, h = bh >> 3, t0 = (id5 & 31) * 64;
  const int tid = threadIdx.x, lane = tid & 63, wv = tid >> 6, wrow0 = wv * 16;
  const size_t hoff = (size_t)h * 193;
  const int prow = tid >> 2, pc0 = (tid & 3) * 16;
  const size_t mb = (size_t)id5 * 4096;

  for (int i = 0; i < 16; ++i) {
    int row = i * 4 + wv;
    size_t gb = ((size_t)(t0 + row) * B_ + b) * QKVB_ + hoff;
    float q = qkvb[gb + lane];
    float k = qkvb[gb + 64 + lane];
    float w0 = qkvb[gb + 128 + lane];
    float mq = q, mk = k;
    #pragma unroll
    for (int off = 32; off; off >>= 1) {
      mq = fmaxf(mq, __shfl_xor(mq, off));
      mk = fmaxf(mk, __shfl_xor(mk, off));
    }
    float eq = __expf(q - mq), ek = __expf(k - mk);
    float sq = eq, sk = ek;
    #pragma unroll
    for (int off = 32; off; off >>= 1) { sq += __shfl_xor(sq, off); sk += __shfl_xor(sk, off); }
    Qb[row * 72 + lane]  = f2bf(eq / sq);
    Kb[row * 72 + lane]  = f2bf(ek / sk);
    W0b[row * 72 + lane] = f2bf(w0);
  }
  {
    uint4 c0v = *(const uint4*)&CKg[mb + prow * 64 + pc0];
    uint4 c1v = *(const uint4*)&CKg[mb + prow * 64 + pc0 + 8];
    uint4 u0v = *(const uint4*)&U0Tg[mb + prow * 64 + pc0];
    uint4 u1v = *(const uint4*)&U0Tg[mb + prow * 64 + pc0 + 8];
    *(short8*)&CKb[prow * 72 + pc0]      = __builtin_bit_cast(short8, c0v);
    *(short8*)&CKb[prow * 72 + pc0 + 8]  = __builtin_bit_cast(short8, c1v);
    *(short8*)&U0Tb[prow * 72 + pc0]     = __builtin_bit_cast(short8, u0v);
    *(short8*)&U0Tb[prow * 72 + pc0 + 8] = __builtin_bit_cast(short8, u1v);
  }
  __syncthreads();

  f32x4 ag[4] = {}, ac[4] = {}, ab[4] = {};
  prod64<72, 72>(Qb, Kb, wrow0, lane, ag);
  prod64<72, 72>(W0b, CKb, wrow0, lane, ac);
  prod64<72, 72>(Qb, W0b, wrow0, lane, ab);

  #pragma unroll
  for (int c0 = 0; c0 < 4; ++c0)
    #pragma unroll
    for (int j = 0; j < 4; ++j) {
      int row = wrow0 + (lane >> 4) * 4 + j, col = c0 * 16 + (lane & 15);
      Gb[row * 72 + col]  = f2bf(col <= row ? ag[c0][j] : 0.f);
      UTb[row * 72 + col] = f2bf(bf2f(U0Tb[row * 72 + col]) - ac[c0][j]);
    }
  __syncthreads();

  prod64<72, 72>(Gb, UTb, wrow0, lane, ab);

  #pragma unroll
  for (int c0 = 0; c0 < 4; ++c0)
    #pragma unroll
    for (int j = 0; j < 4; ++j) {
      int row = wrow0 + (lane >> 4) * 4 + j, col = c0 * 16 + (lane & 15);
      attnb[((size_t)(t0 + row) * B_ + b) * HID_ + h * 64 + col] = f2bf(ab[c0][j]);
    }
}

// ---------------------------------------------------------------------------
extern "C" void kernel_launch(void* const* d_in, const int* in_sizes, int n_in,
                              void* d_out, int out_size, void* d_ws, size_t ws_size,
                              hipStream_t stream)
{
  const float* x        = (const float*)d_in[0];
  const float* ip_w     = (const float*)d_in[1];
  const float* ip_b     = (const float*)d_in[2];
  const float* fw_ln_g  = (const float*)d_in[3];
  const float* fw_ln_b  = (const float*)d_in[4];
  const float* fw_slow_w = (const float*)d_in[5];
  const float* fw_out_w  = (const float*)d_in[6];
  const float* ff_ln_g  = (const float*)d_in[7];
  const float* ff_ln_b  = (const float*)d_in[8];
  const float* ff_w1    = (const float*)d_in[9];
  const float* ff_b1    = (const float*)d_in[10];
  const float* ff_w2    = (const float*)d_in[11];
  const float* ff_b2    = (const float*)d_in[12];
  float* out = (float*)d_out;

  const int M = B_ * S_;  // 16384
  const size_t matN = (size_t)64 * NCH_ * 4096;
  const int SLOWPAD = 1664;

  const size_t nIp = 512 * 512, nOut = 512 * 512;
  const size_t nSlow = (size_t)SLOWPAD * 512;
  const size_t nW1 = (size_t)FF_ * 512, nW2 = (size_t)512 * FF_;
  const size_t nXbf = (size_t)M * HID_;
  const size_t poolElems = nIp + 2 * nSlow + 2 * nOut + nW1 + nW2 + nXbf;

  size_t need = ((size_t)M * (HID_ + QKVB_ + HID_)) * sizeof(float) + poolElems * 2;
  if (ws_size < need) return;

  float* cur  = (float*)d_ws;
  float* qkvb = cur + (size_t)M * HID_;
  float* attnSlot = qkvb + (size_t)M * QKVB_;
  u16*   MTg  = (u16*)attnSlot;
  u16*   Ng   = MTg + matN;
  u16*   attnb = (u16*)attnSlot;
  u16*   CKg  = (u16*)out;
  u16*   U0Tg = CKg + matN;
  u16*   tmpbf = (u16*)out;
  u16*   hiddenb = (u16*)qkvb;

  u16* pool = (u16*)(attnSlot + (size_t)M * HID_);
  u16* ipwb   = pool;               pool += nIp;
  u16* slowb0 = pool;               pool += nSlow;
  u16* slowb1 = pool;               pool += nSlow;
  u16* outwb0 = pool;               pool += nOut;
  u16* outwb1 = pool;               pool += nOut;
  u16* w1b    = pool;               pool += nW1;
  u16* w2b    = pool;               pool += nW2;
  u16* xbf    = pool;

  dim3 blk(256);

  conv_w<<<(nIp + 255) / 256, blk, 0, stream>>>(ip_w, ipwb, nIp, nIp);
  conv_w<<<(nSlow + 255) / 256, blk, 0, stream>>>(fw_slow_w, slowb0, QKVB_ * 512, nSlow);
  conv_w<<<(nSlow + 255) / 256, blk, 0, stream>>>(fw_slow_w + (size_t)QKVB_ * 512, slowb1, QKVB_ * 512, nSlow);
  conv_w<<<(nOut + 255) / 256, blk, 0, stream>>>(fw_out_w, outwb0, nOut, nOut);
  conv_w<<<(nOut + 255) / 256, blk, 0, stream>>>(fw_out_w + (size_t)512 * 512, outwb1, nOut, nOut);
  conv_w<<<(nW1 + 255) / 256, blk, 0, stream>>>(ff_w1, w1b, nW1, nW1);
  conv_w<<<(nW2 + 255) / 256, blk, 0, stream>>>(ff_w2, w2b, nW2, nW2);
  conv_x<<<M, 64, 0, stream>>>(x, xbf);

  gemm_bf<true, false, false, false, false><<<dim3(4, 128), blk, 0, stream>>>(
      xbf, ipwb, ip_b, nullptr, cur, M, HID_, HID_);

  for (int layer = 0; layer < 2; ++layer) {
    u16* slowb = layer ? slowb1 : slowb0;
    u16* outwb = layer ? outwb1 : outwb0;

    ln_bf<<<M, 64, 0, stream>>>(cur, fw_ln_g + layer * HID_, fw_ln_b + layer * HID_, tmpbf);
    gemm_bf<false, false, false, false, false><<<dim3(13, 128), blk, 0, stream>>>(
        tmpbf, slowb, nullptr, nullptr, qkvb, M, QKVB_, HID_);
    delta_p1<<<64 * NCH_, 256, 0, stream>>>(qkvb, MTg, Ng, CKg, U0Tg);
    delta_p2<<<64, 256, 0, stream>>>(MTg, Ng, qkvb);
    delta_p3<<<64 * NCH_, 256, 0, stream>>>(qkvb, CKg, U0Tg, attnb);
    if (layer == 0) {
      gemm_bf<false, false, true, false, false><<<dim3(4, 128), blk, 0, stream>>>(
          attnb, outwb, nullptr, cur, cur, M, HID_, HID_);
      ln_bf<<<M, 64, 0, stream>>>(cur, ff_ln_g, ff_ln_b, tmpbf);
      gemm_bf<true, true, false, true, false><<<dim3(16, 128), blk, 0, stream>>>(
          tmpbf, w1b, ff_b1, nullptr, hiddenb, M, FF_, HID_);
      gemm_bf<true, false, true, false, false><<<dim3(4, 128), blk, 0, stream>>>(
          hiddenb, w2b, ff_b2, cur, cur, M, HID_, FF_);
    } else {
      // final out-proj writes [B,S,512] directly (fused transpose)
      gemm_bf<false, false, true, false, true><<<dim3(4, 128), blk, 0, stream>>>(
          attnb, outwb, nullptr, cur, out, M, HID_, HID_);
    }
  }
}

// Round 8
// 601.833 us; speedup vs baseline: 1.2352x; 1.2352x over previous
//
#include <hip/hip_runtime.h>
#include <hip/hip_bf16.h>

#define B_    8
#define S_    2048
#define HID_  512
#define H_    8
#define D_    64
#define FF_   2048
#define QN_   1664   // padded qkvb width: q 512 | k 512 | v 512 | beta 8 (pad 128)
#define NCH_  32     // S/64 chunks
#define SLOWSTRIDE (1544 * 512)   // fw_slow_w per-layer stride (floats)

typedef unsigned short u16;
typedef __attribute__((ext_vector_type(8))) short short8;
typedef __attribute__((ext_vector_type(4))) float f32x4;

__device__ __forceinline__ u16 f2bf(float x) {           // RNE fp32->bf16
  unsigned u = __builtin_bit_cast(unsigned, x);
  unsigned r = (u + 0x7FFFu + ((u >> 16) & 1u)) >> 16;
  return (u16)r;
}
__device__ __forceinline__ float bf2f(u16 v) {
  return __builtin_bit_cast(float, (unsigned)v << 16);
}
__device__ __forceinline__ void gload16(const void* g, void* l) {
  __builtin_amdgcn_global_load_lds(
      (const __attribute__((address_space(1))) unsigned int*)g,
      (__attribute__((address_space(3))) unsigned int*)l, 16, 0, 0);
}

// 64x64x64 product C[r][c] = sum_k F[r][k]*G[c][k], bf16 LDS operands.
template<int FS, int GS>
__device__ __forceinline__ void prod64(const u16* __restrict__ F,
                                       const u16* __restrict__ G,
                                       int wrow0, int lane, f32x4 acc[4])
{
  short8 f0 = *(const short8*)&F[(wrow0 + (lane & 15)) * FS + ((lane >> 4) * 8)];
  short8 f1 = *(const short8*)&F[(wrow0 + (lane & 15)) * FS + 32 + ((lane >> 4) * 8)];
  #pragma unroll
  for (int c0 = 0; c0 < 4; ++c0) {
    short8 g0 = *(const short8*)&G[(c0 * 16 + (lane & 15)) * GS + ((lane >> 4) * 8)];
    short8 g1 = *(const short8*)&G[(c0 * 16 + (lane & 15)) * GS + 32 + ((lane >> 4) * 8)];
    acc[c0] = __builtin_amdgcn_mfma_f32_16x16x32_bf16(f0, g0, acc[c0], 0, 0, 0);
    acc[c0] = __builtin_amdgcn_mfma_f32_16x16x32_bf16(f1, g1, acc[c0], 0, 0, 0);
  }
}

// ---------------------------------------------------------------------------
// bf16 GEMM, global_load_lds staging, both-sides swizzle.
// TRANS: write output [S,B]->[B,S] transposed.
// QKVB: fused softmax(q,k)/sigmoid(beta) epilogue (head-aligned layout).
// ---------------------------------------------------------------------------
template<bool BIAS, bool RELU, bool RES, bool OUTBF, bool TRANS, bool QKVB>
__global__ __launch_bounds__(256) void gemm_bf(
    const u16* __restrict__ A, const u16* __restrict__ W,
    const float* __restrict__ bias, const float* __restrict__ res,
    void* __restrict__ Cout, int M, int N, int K)
{
  __shared__ __align__(16) u16 As[128 * 64];
  __shared__ __align__(16) u16 Bs[128 * 64];
  const int tid = threadIdx.x, lane = tid & 63, wv = tid >> 6;
  const int bm = blockIdx.y * 128, bn = blockIdx.x * 128;
  const int wr = wv >> 1, wc = wv & 1;
  const int row16 = lane & 15, kg = lane >> 4;
  const int srow = lane >> 3;
  const int soff = ((lane & 7) * 16) ^ (srow << 4);

  f32x4 acc[4][4] = {};
  const int ktiles = K >> 6;

  for (int kt = 0; kt < ktiles; ++kt) {
    #pragma unroll
    for (int i = 0; i < 4; ++i) {
      const int r = i * 32 + wv * 8;
      const char* ga = (const char*)(A + (size_t)(bm + r + srow) * K + (size_t)kt * 64) + soff;
      gload16(ga, &As[r * 64]);
      const char* gw = (const char*)(W + (size_t)(bn + r + srow) * K + (size_t)kt * 64) + soff;
      gload16(gw, &Bs[r * 64]);
    }
    __syncthreads();

    #pragma unroll
    for (int kh = 0; kh < 2; ++kh) {
      const int fb = ((kh * 64 + kg * 16) ^ ((row16 & 7) << 4)) >> 1;
      short8 af[4], bf_[4];
      #pragma unroll
      for (int m = 0; m < 4; ++m)
        af[m] = *(const short8*)&As[(wr * 64 + m * 16 + row16) * 64 + fb];
      #pragma unroll
      for (int n = 0; n < 4; ++n)
        bf_[n] = *(const short8*)&Bs[(wc * 64 + n * 16 + row16) * 64 + fb];
      #pragma unroll
      for (int m = 0; m < 4; ++m)
        #pragma unroll
        for (int n = 0; n < 4; ++n)
          acc[m][n] = __builtin_amdgcn_mfma_f32_16x16x32_bf16(af[m], bf_[n], acc[m][n], 0, 0, 0);
    }
    __syncthreads();
  }

  if (QKVB) {
    const int span0 = bn + wc * 64;           // wave-uniform 64-col head span
    #pragma unroll
    for (int m = 0; m < 4; ++m) {
      #pragma unroll
      for (int j = 0; j < 4; ++j) {
        if (span0 < 1024) {                   // q or k: row softmax over 64 cols
          float v0 = acc[m][0][j], v1 = acc[m][1][j];
          float v2 = acc[m][2][j], v3 = acc[m][3][j];
          float mx = fmaxf(fmaxf(v0, v1), fmaxf(v2, v3));
          #pragma unroll
          for (int off = 1; off < 16; off <<= 1) mx = fmaxf(mx, __shfl_xor(mx, off));
          float e0 = __expf(v0 - mx), e1 = __expf(v1 - mx);
          float e2 = __expf(v2 - mx), e3 = __expf(v3 - mx);
          float s = (e0 + e1) + (e2 + e3);
          #pragma unroll
          for (int off = 1; off < 16; off <<= 1) s += __shfl_xor(s, off);
          float r = 1.f / s;
          acc[m][0][j] = e0 * r; acc[m][1][j] = e1 * r;
          acc[m][2][j] = e2 * r; acc[m][3][j] = e3 * r;
        } else if (span0 >= 1536) {           // beta cols: sigmoid
          #pragma unroll
          for (int n = 0; n < 4; ++n)
            acc[m][n][j] = 1.f / (1.f + __expf(-acc[m][n][j]));
        }
      }
    }
  }

  #pragma unroll
  for (int m = 0; m < 4; ++m) {
    #pragma unroll
    for (int n = 0; n < 4; ++n) {
      const int gcol = bn + wc * 64 + n * 16 + row16;
      if (gcol < N) {
        #pragma unroll
        for (int j = 0; j < 4; ++j) {
          const int grow = bm + wr * 64 + m * 16 + kg * 4 + j;
          float v = acc[m][n][j];
          if (BIAS) v += bias[gcol];
          if (RES)  v += res[(size_t)grow * N + gcol];
          if (RELU) v = fmaxf(v, 0.f);
          size_t di;
          if (TRANS) di = ((size_t)(grow & 7) * S_ + (grow >> 3)) * N + gcol;
          else       di = (size_t)grow * N + gcol;
          if (OUTBF) ((u16*)Cout)[di] = f2bf(v);
          else       ((float*)Cout)[di] = v;
        }
      }
    }
  }
}

// ---------------------------------------------------------------------------
__global__ __launch_bounds__(256) void conv_w(const float* __restrict__ s,
                                              u16* __restrict__ d, int n, int npad)
{
  int i = blockIdx.x * 256 + threadIdx.x;
  if (i < npad) d[i] = (i < n) ? f2bf(s[i]) : (u16)0;
}

// slow_w reordered head-aligned: rows [q 512 | k 512 | v 512 | beta 8 | pad]
__global__ __launch_bounds__(256) void conv_slow(const float* __restrict__ s,
                                                 u16* __restrict__ d)
{
  int r = blockIdx.x;
  int src;
  if (r < 512)       src = (r >> 6) * 193 + (r & 63);
  else if (r < 1024) src = ((r - 512) >> 6) * 193 + 64 + (r & 63);
  else if (r < 1536) src = ((r - 1024) >> 6) * 193 + 128 + (r & 63);
  else if (r < 1544) src = (r - 1536) * 193 + 192;
  else               src = -1;
  for (int c = threadIdx.x; c < 512; c += 256)
    d[(size_t)r * 512 + c] = (src >= 0) ? f2bf(s[(size_t)src * 512 + c]) : (u16)0;
}

__global__ __launch_bounds__(64) void conv_x(const float* __restrict__ x,
                                             u16* __restrict__ xbf)
{
  size_t m = blockIdx.x;
  size_t s = m >> 3, b = m & 7;
  const float4* src = (const float4*)(x + (b * (size_t)S_ + s) * HID_);
  float4 v0 = src[threadIdx.x], v1 = src[64 + threadIdx.x];
  u16* dst = xbf + m * HID_;
  uint2 p0, p1;
  p0.x = (unsigned)f2bf(v0.x) | ((unsigned)f2bf(v0.y) << 16);
  p0.y = (unsigned)f2bf(v0.z) | ((unsigned)f2bf(v0.w) << 16);
  p1.x = (unsigned)f2bf(v1.x) | ((unsigned)f2bf(v1.y) << 16);
  p1.y = (unsigned)f2bf(v1.z) | ((unsigned)f2bf(v1.w) << 16);
  *(uint2*)&dst[threadIdx.x * 4] = p0;
  *(uint2*)&dst[256 + threadIdx.x * 4] = p1;
}

__global__ __launch_bounds__(64) void ln_bf(const float* __restrict__ x,
    const float* __restrict__ g, const float* __restrict__ bt,
    u16* __restrict__ o)
{
  size_t row = blockIdx.x;
  int lane = threadIdx.x;
  const float4* xr = (const float4*)(x + row * HID_);
  float4 v0 = xr[lane];
  float4 v1 = xr[64 + lane];
  float s  = v0.x + v0.y + v0.z + v0.w + v1.x + v1.y + v1.z + v1.w;
  float ss = v0.x*v0.x + v0.y*v0.y + v0.z*v0.z + v0.w*v0.w
           + v1.x*v1.x + v1.y*v1.y + v1.z*v1.z + v1.w*v1.w;
  #pragma unroll
  for (int off = 32; off; off >>= 1) {
    s  += __shfl_xor(s, off);
    ss += __shfl_xor(ss, off);
  }
  float mean = s * (1.f / HID_);
  float inv  = rsqrtf(ss * (1.f / HID_) - mean * mean + 1e-5f);
  const float4* gv = (const float4*)g;
  const float4* bv = (const float4*)bt;
  float4 g0 = gv[lane], g1 = gv[64 + lane];
  float4 b0 = bv[lane], b1 = bv[64 + lane];
  uint2 p0, p1;
  p0.x = (unsigned)f2bf((v0.x - mean) * inv * g0.x + b0.x)
       | ((unsigned)f2bf((v0.y - mean) * inv * g0.y + b0.y) << 16);
  p0.y = (unsigned)f2bf((v0.z - mean) * inv * g0.z + b0.z)
       | ((unsigned)f2bf((v0.w - mean) * inv * g0.w + b0.w) << 16);
  p1.x = (unsigned)f2bf((v1.x - mean) * inv * g1.x + b1.x)
       | ((unsigned)f2bf((v1.y - mean) * inv * g1.y + b1.y) << 16);
  p1.y = (unsigned)f2bf((v1.z - mean) * inv * g1.z + b1.z)
       | ((unsigned)f2bf((v1.w - mean) * inv * g1.w + b1.w) << 16);
  u16* ov = o + row * HID_;
  *(uint2*)&ov[lane * 4] = p0;
  *(uint2*)&ov[256 + lane * 4] = p1;
}

// ---------------------------------------------------------------------------
// Delta rule 3-phase (R6 substitution structure, bf16 qkvb inputs).
// ---------------------------------------------------------------------------
__global__ __launch_bounds__(256, 2) void delta_p1(const u16* __restrict__ qf,
                                                   u16* __restrict__ MTg,
                                                   u16* __restrict__ Ng,
                                                   u16* __restrict__ CKg,
                                                   u16* __restrict__ U0Tg)
{
  __shared__ __align__(16) u16 Kb[64 * 72];
  __shared__ __align__(16) float Am[64][65];
  __shared__ __align__(16) float Uv[64][65];
  __shared__ __align__(16) float Uk[64][65];
  __shared__ __align__(16) u16 CKTb[64 * 72];
  __shared__ __align__(16) u16 U0Tb[64 * 72];
  __shared__ float bet[64];
  u16* KTb = (u16*)&Am[0][0];   // stride 88, aliased (Am dead post-solve)

  const int id5 = blockIdx.x, bh = id5 >> 5;
  const int b = bh & 7, h = bh >> 3, t0 = (id5 & 31) * 64;
  const int tid = threadIdx.x, lane = tid & 63, wv = tid >> 6;
  const int wid = wv, wrow0 = wv * 16;

  #pragma unroll
  for (int p = 0; p < 2; ++p) {
    int linear = p * 256 + tid, row = linear >> 3, seg = linear & 7;
    uint4 k4 = *(const uint4*)&qf[((size_t)(t0 + row) * B_ + b) * QN_ + 512 + h * 64 + seg * 8];
    *(short8*)&Kb[row * 72 + seg * 8] = __builtin_bit_cast(short8, k4);
  }
  if (tid < 64) bet[tid] = bf2f(qf[((size_t)(t0 + tid) * B_ + b) * QN_ + 1536 + h]);
  __syncthreads();

  // A = beta ⊙ K K^T (MFMA)
  {
    f32x4 a[4] = {};
    prod64<72, 72>(Kb, Kb, wrow0, lane, a);
    #pragma unroll
    for (int c0 = 0; c0 < 4; ++c0)
      #pragma unroll
      for (int j = 0; j < 4; ++j) {
        int row = wrow0 + (lane >> 4) * 4 + j, col = c0 * 16 + (lane & 15);
        Am[row][col] = bet[row] * a[c0][j];
      }
  }
  // Uv = beta*V, Uk = beta*K (fp32)
  #pragma unroll
  for (int p = 0; p < 2; ++p) {
    int linear = p * 256 + tid, row = linear >> 3, seg = linear & 7;
    float bt_ = bet[row];
    uint4 v4 = *(const uint4*)&qf[((size_t)(t0 + row) * B_ + b) * QN_ + 1024 + h * 64 + seg * 8];
    short8 vs = __builtin_bit_cast(short8, v4);
    short8 ks = *(const short8*)&Kb[row * 72 + seg * 8];
    #pragma unroll
    for (int e = 0; e < 8; ++e) {
      Uv[row][seg * 8 + e] = bt_ * bf2f((u16)vs[e]);
      Uk[row][seg * 8 + e] = bt_ * bf2f((u16)ks[e]);
    }
  }
  __syncthreads();

  // two-RHS blocked forward substitution: (I+A){U0,CK} = {bV,bK}
  #pragma unroll 1
  for (int blk = 0; blk < 4; ++blk) {
    if (wid == blk) {
      const int r0 = blk * 16;
      float uv[16], uk[16];
      #pragma unroll
      for (int i = 0; i < 16; ++i) { uv[i] = Uv[r0 + i][lane]; uk[i] = Uk[r0 + i][lane]; }
      #pragma unroll
      for (int jj = 0; jj < 15; ++jj) {
        #pragma unroll
        for (int t = jj + 1; t < 16; ++t) {
          float a = Am[r0 + t][r0 + jj];
          uv[t] = fmaf(-a, uv[jj], uv[t]);
          uk[t] = fmaf(-a, uk[jj], uk[t]);
        }
      }
      #pragma unroll
      for (int i = 0; i < 16; ++i) { Uv[r0 + i][lane] = uv[i]; Uk[r0 + i][lane] = uk[i]; }
    }
    __syncthreads();
    if (wid > blk) {
      const int r0 = blk * 16, rw = wid * 16;
      float uv[16], uk[16];
      #pragma unroll
      for (int i = 0; i < 16; ++i) { uv[i] = Uv[rw + i][lane]; uk[i] = Uk[rw + i][lane]; }
      #pragma unroll
      for (int jj = 0; jj < 16; ++jj) {
        float sv = Uv[r0 + jj][lane], sk = Uk[r0 + jj][lane];
        #pragma unroll
        for (int i = 0; i < 16; ++i) {
          float a = Am[rw + i][r0 + jj];
          uv[i] = fmaf(-a, sv, uv[i]);
          uk[i] = fmaf(-a, sk, uk[i]);
        }
      }
      #pragma unroll
      for (int i = 0; i < 16; ++i) { Uv[rw + i][lane] = uv[i]; Uk[rw + i][lane] = uk[i]; }
    }
    __syncthreads();
  }

  const int prow = tid >> 2, pc0 = (tid & 3) * 16;
  const size_t mb = (size_t)id5 * 4096;
  {
    union { u16 u[16]; uint4 v[2]; } pk, pu;
    #pragma unroll
    for (int i = 0; i < 16; ++i) pk.u[i] = f2bf(Uk[prow][pc0 + i]);   // CK[t][d]
    #pragma unroll
    for (int i = 0; i < 16; ++i) pu.u[i] = f2bf(Uv[pc0 + i][prow]);   // U0T[d][t]
    *(uint4*)&CKg[mb + prow * 64 + pc0]      = pk.v[0];
    *(uint4*)&CKg[mb + prow * 64 + pc0 + 8]  = pk.v[1];
    *(uint4*)&U0Tg[mb + prow * 64 + pc0]     = pu.v[0];
    *(uint4*)&U0Tg[mb + prow * 64 + pc0 + 8] = pu.v[1];
    *(short8*)&U0Tb[prow * 72 + pc0]     = *(short8*)&pu.u[0];
    *(short8*)&U0Tb[prow * 72 + pc0 + 8] = *(short8*)&pu.u[8];
    #pragma unroll
    for (int i = 0; i < 16; ++i) CKTb[prow * 72 + pc0 + i] = f2bf(Uk[pc0 + i][prow]);
    #pragma unroll
    for (int i = 0; i < 16; ++i) KTb[prow * 88 + pc0 + i] = Kb[(pc0 + i) * 72 + prow];
  }
  __syncthreads();

  // MT = K^T CK, N = U0^T K (MFMA)
  {
    f32x4 am[4] = {}, an[4] = {};
    prod64<88, 72>(KTb, CKTb, wrow0, lane, am);
    prod64<72, 88>(U0Tb, KTb, wrow0, lane, an);
    #pragma unroll
    for (int c0 = 0; c0 < 4; ++c0)
      #pragma unroll
      for (int j = 0; j < 4; ++j) {
        int row = wrow0 + (lane >> 4) * 4 + j, col = c0 * 16 + (lane & 15);
        MTg[mb + (size_t)row * 64 + col] = f2bf(am[c0][j]);
        Ng[mb + (size_t)row * 64 + col]  = f2bf(an[c0][j]);
      }
  }
}

__global__ __launch_bounds__(256, 1) void delta_p2(const u16* __restrict__ MTg,
                                                   const u16* __restrict__ Ng,
                                                   u16* __restrict__ Wsnap)
{
  __shared__ float Ws[64][65];
  __shared__ __align__(16) u16 Wbf[64 * 72];
  __shared__ __align__(16) u16 MTb[64 * 72];
  __shared__ __align__(16) u16 Nb[64 * 72];
  const int bh = blockIdx.x;
  const int tid = threadIdx.x, lane = tid & 63, wv = tid >> 6, wrow0 = wv * 16;
  const int prow = tid >> 2, pc0 = (tid & 3) * 16;

  for (int i = tid; i < 64 * 65; i += 256) (&Ws[0][0])[i] = 0.f;
  for (int i = tid; i < 64 * 72; i += 256) Wbf[i] = 0;
  __syncthreads();

  size_t base = (size_t)bh * NCH_ * 4096;
  uint4 rm0 = *(const uint4*)&MTg[base + prow * 64 + pc0];
  uint4 rm1 = *(const uint4*)&MTg[base + prow * 64 + pc0 + 8];
  uint4 rn0 = *(const uint4*)&Ng[base + prow * 64 + pc0];
  uint4 rn1 = *(const uint4*)&Ng[base + prow * 64 + pc0 + 8];

  for (int j = 0; j < NCH_; ++j) {
    *(short8*)&MTb[prow * 72 + pc0]     = __builtin_bit_cast(short8, rm0);
    *(short8*)&MTb[prow * 72 + pc0 + 8] = __builtin_bit_cast(short8, rm1);
    *(short8*)&Nb[prow * 72 + pc0]      = __builtin_bit_cast(short8, rn0);
    *(short8*)&Nb[prow * 72 + pc0 + 8]  = __builtin_bit_cast(short8, rn1);
    {
      size_t sb = base + (size_t)j * 4096;
      short8 w0 = *(const short8*)&Wbf[prow * 72 + pc0];
      short8 w1 = *(const short8*)&Wbf[prow * 72 + pc0 + 8];
      *(uint4*)&Wsnap[sb + prow * 64 + pc0]     = __builtin_bit_cast(uint4, w0);
      *(uint4*)&Wsnap[sb + prow * 64 + pc0 + 8] = __builtin_bit_cast(uint4, w1);
    }
    if (j + 1 < NCH_) {
      size_t nb2 = base + (size_t)(j + 1) * 4096;
      rm0 = *(const uint4*)&MTg[nb2 + prow * 64 + pc0];
      rm1 = *(const uint4*)&MTg[nb2 + prow * 64 + pc0 + 8];
      rn0 = *(const uint4*)&Ng[nb2 + prow * 64 + pc0];
      rn1 = *(const uint4*)&Ng[nb2 + prow * 64 + pc0 + 8];
    }
    __syncthreads();
    f32x4 a[4] = {};
    prod64<72, 72>(Wbf, MTb, wrow0, lane, a);
    #pragma unroll
    for (int c0 = 0; c0 < 4; ++c0)
      #pragma unroll
      for (int jj = 0; jj < 4; ++jj) {
        int row = wrow0 + (lane >> 4) * 4 + jj, col = c0 * 16 + (lane & 15);
        float w = Ws[row][col] + bf2f(Nb[row * 72 + col]) - a[c0][jj];
        Ws[row][col] = w;
        Wbf[row * 72 + col] = f2bf(w);
      }
    __syncthreads();
  }
}

__global__ __launch_bounds__(256, 2) void delta_p3(const u16* __restrict__ qf,
                                                   const u16* __restrict__ Wsnap,
                                                   const u16* __restrict__ CKg,
                                                   const u16* __restrict__ U0Tg,
                                                   u16* __restrict__ attnb)
{
  __shared__ __align__(16) u16 Qb[64 * 72];
  __shared__ __align__(16) u16 Kb[64 * 72];
  __shared__ __align__(16) u16 W0b[64 * 72];
  __shared__ __align__(16) u16 CKb[64 * 72];
  __shared__ __align__(16) u16 U0Tb[64 * 72];
  __shared__ __align__(16) u16 Gb[64 * 72];
  __shared__ __align__(16) u16 UTb[64 * 72];

  const int id5 = blockIdx.x, bh = id5 >> 5;
  const int b = bh & 7, h = bh >> 3, t0 = (id5 & 31) * 64;
  const int tid = threadIdx.x, lane = tid & 63, wv = tid >> 6, wrow0 = wv * 16;
  const int prow = tid >> 2, pc0 = (tid & 3) * 16;
  const size_t mb = (size_t)id5 * 4096;

  #pragma unroll
  for (int p = 0; p < 2; ++p) {
    int linear = p * 256 + tid, row = linear >> 3, seg = linear & 7;
    size_t gb = ((size_t)(t0 + row) * B_ + b) * QN_;
    uint4 q4 = *(const uint4*)&qf[gb + h * 64 + seg * 8];
    uint4 k4 = *(const uint4*)&qf[gb + 512 + h * 64 + seg * 8];
    uint4 w4 = *(const uint4*)&Wsnap[mb + (size_t)row * 64 + seg * 8];
    *(short8*)&Qb[row * 72 + seg * 8]  = __builtin_bit_cast(short8, q4);
    *(short8*)&Kb[row * 72 + seg * 8]  = __builtin_bit_cast(short8, k4);
    *(short8*)&W0b[row * 72 + seg * 8] = __builtin_bit_cast(short8, w4);
  }
  {
    uint4 c0v = *(const uint4*)&CKg[mb + prow * 64 + pc0];
    uint4 c1v = *(const uint4*)&CKg[mb + prow * 64 + pc0 + 8];
    uint4 u0v = *(const uint4*)&U0Tg[mb + prow * 64 + pc0];
    uint4 u1v = *(const uint4*)&U0Tg[mb + prow * 64 + pc0 + 8];
    *(short8*)&CKb[prow * 72 + pc0]      = __builtin_bit_cast(short8, c0v);
    *(short8*)&CKb[prow * 72 + pc0 + 8]  = __builtin_bit_cast(short8, c1v);
    *(short8*)&U0Tb[prow * 72 + pc0]     = __builtin_bit_cast(short8, u0v);
    *(short8*)&U0Tb[prow * 72 + pc0 + 8] = __builtin_bit_cast(short8, u1v);
  }
  __syncthreads();

  f32x4 ag[4] = {}, ac[4] = {}, ab[4] = {};
  prod64<72, 72>(Qb, Kb, wrow0, lane, ag);    // QK^T
  prod64<72, 72>(W0b, CKb, wrow0, lane, ac);  // (W0·CK^T)[d][t]
  prod64<72, 72>(Qb, W0b, wrow0, lane, ab);   // Q·W0^T

  #pragma unroll
  for (int c0 = 0; c0 < 4; ++c0)
    #pragma unroll
    for (int j = 0; j < 4; ++j) {
      int row = wrow0 + (lane >> 4) * 4 + j, col = c0 * 16 + (lane & 15);
      Gb[row * 72 + col]  = f2bf(col <= row ? ag[c0][j] : 0.f);
      UTb[row * 72 + col] = f2bf(bf2f(U0Tb[row * 72 + col]) - ac[c0][j]);
    }
  __syncthreads();

  prod64<72, 72>(Gb, UTb, wrow0, lane, ab);   // += G·U

  #pragma unroll
  for (int c0 = 0; c0 < 4; ++c0)
    #pragma unroll
    for (int j = 0; j < 4; ++j) {
      int row = wrow0 + (lane >> 4) * 4 + j, col = c0 * 16 + (lane & 15);
      attnb[((size_t)(t0 + row) * B_ + b) * HID_ + h * 64 + col] = f2bf(ab[c0][j]);
    }
}

// ---------------------------------------------------------------------------
extern "C" void kernel_launch(void* const* d_in, const int* in_sizes, int n_in,
                              void* d_out, int out_size, void* d_ws, size_t ws_size,
                              hipStream_t stream)
{
  const float* x        = (const float*)d_in[0];
  const float* ip_w     = (const float*)d_in[1];
  const float* ip_b     = (const float*)d_in[2];
  const float* fw_ln_g  = (const float*)d_in[3];
  const float* fw_ln_b  = (const float*)d_in[4];
  const float* fw_slow_w = (const float*)d_in[5];
  const float* fw_out_w  = (const float*)d_in[6];
  const float* ff_ln_g  = (const float*)d_in[7];
  const float* ff_ln_b  = (const float*)d_in[8];
  const float* ff_w1    = (const float*)d_in[9];
  const float* ff_b1    = (const float*)d_in[10];
  const float* ff_w2    = (const float*)d_in[11];
  const float* ff_b2    = (const float*)d_in[12];
  float* out = (float*)d_out;

  const int M = B_ * S_;  // 16384
  const size_t matN = (size_t)64 * NCH_ * 4096;   // 8.39M elems

  const size_t nIp = 512 * 512, nOut = 512 * 512;
  const size_t nSlow = (size_t)QN_ * 512;
  const size_t nW1 = (size_t)FF_ * 512, nW2 = (size_t)512 * FF_;
  const size_t nXbf = (size_t)M * HID_;
  const size_t poolElems = nIp + 2 * nSlow + 2 * nOut + nW1 + nW2 + nXbf + matN;

  size_t need = (size_t)M * HID_ * 4
              + ((size_t)M * QN_ + 2 * matN + poolElems) * 2;
  if (ws_size < need) return;

  float* cur   = (float*)d_ws;
  u16*   qkvbf = (u16*)(cur + (size_t)M * HID_);            // [M][1664] bf16
  u16*   attnSlot = qkvbf + (size_t)M * QN_;                // 2*matN u16
  u16*   MTg   = attnSlot;
  u16*   Ng    = MTg + matN;
  u16*   attnb = attnSlot;                                  // reuses MTg after p2
  u16*   CKg   = (u16*)out;
  u16*   U0Tg  = CKg + matN;
  u16*   tmpbf = (u16*)out;                                 // LN out; dead when CKg live
  u16*   hiddenb = qkvbf;                                   // FFN hidden (qkvbf+attn dead)

  u16* pool = attnSlot + 2 * matN;
  u16* ipwb   = pool;               pool += nIp;
  u16* slowb0 = pool;               pool += nSlow;
  u16* slowb1 = pool;               pool += nSlow;
  u16* outwb0 = pool;               pool += nOut;
  u16* outwb1 = pool;               pool += nOut;
  u16* w1b    = pool;               pool += nW1;
  u16* w2b    = pool;               pool += nW2;
  u16* Wsnap  = pool;               pool += matN;
  u16* xbf    = pool;

  dim3 blk(256);

  conv_w<<<(nIp + 255) / 256, blk, 0, stream>>>(ip_w, ipwb, nIp, nIp);
  conv_slow<<<QN_, blk, 0, stream>>>(fw_slow_w, slowb0);
  conv_slow<<<QN_, blk, 0, stream>>>(fw_slow_w + (size_t)SLOWSTRIDE, slowb1);
  conv_w<<<(nOut + 255) / 256, blk, 0, stream>>>(fw_out_w, outwb0, nOut, nOut);
  conv_w<<<(nOut + 255) / 256, blk, 0, stream>>>(fw_out_w + (size_t)512 * 512, outwb1, nOut, nOut);
  conv_w<<<(nW1 + 255) / 256, blk, 0, stream>>>(ff_w1, w1b, nW1, nW1);
  conv_w<<<(nW2 + 255) / 256, blk, 0, stream>>>(ff_w2, w2b, nW2, nW2);
  conv_x<<<M, 64, 0, stream>>>(x, xbf);

  gemm_bf<true, false, false, false, false, false><<<dim3(4, 128), blk, 0, stream>>>(
      xbf, ipwb, ip_b, nullptr, cur, M, HID_, HID_);

  for (int layer = 0; layer < 2; ++layer) {
    u16* slowb = layer ? slowb1 : slowb0;
    u16* outwb = layer ? outwb1 : outwb0;

    ln_bf<<<M, 64, 0, stream>>>(cur, fw_ln_g + layer * HID_, fw_ln_b + layer * HID_, tmpbf);
    gemm_bf<false, false, false, true, false, true><<<dim3(13, 128), blk, 0, stream>>>(
        tmpbf, slowb, nullptr, nullptr, qkvbf, M, QN_, HID_);
    delta_p1<<<64 * NCH_, 256, 0, stream>>>(qkvbf, MTg, Ng, CKg, U0Tg);
    delta_p2<<<64, 256, 0, stream>>>(MTg, Ng, Wsnap);
    delta_p3<<<64 * NCH_, 256, 0, stream>>>(qkvbf, Wsnap, CKg, U0Tg, attnb);
    if (layer == 0) {
      gemm_bf<false, false, true, false, false, false><<<dim3(4, 128), blk, 0, stream>>>(
          attnb, outwb, nullptr, cur, cur, M, HID_, HID_);
      ln_bf<<<M, 64, 0, stream>>>(cur, ff_ln_g, ff_ln_b, tmpbf);
      gemm_bf<true, true, false, true, false, false><<<dim3(16, 128), blk, 0, stream>>>(
          tmpbf, w1b, ff_b1, nullptr, hiddenb, M, FF_, HID_);
      gemm_bf<true, false, true, false, false, false><<<dim3(4, 128), blk, 0, stream>>>(
          hiddenb, w2b, ff_b2, cur, cur, M, HID_, FF_);
    } else {
      // final out-proj writes [B,S,512] directly (fused transpose)
      gemm_bf<false, false, true, false, true, false><<<dim3(4, 128), blk, 0, stream>>>(
          attnb, outwb, nullptr, cur, out, M, HID_, HID_);
    }
  }
}

// Round 9
// 560.071 us; speedup vs baseline: 1.3273x; 1.0746x over previous
//
#include <hip/hip_runtime.h>
#include <hip/hip_bf16.h>

#define B_    8
#define S_    2048
#define HID_  512
#define H_    8
#define D_    64
#define FF_   2048
#define QN_   1664   // padded qkvb width: q 512 | k 512 | v 512 | beta 8 (pad 128)
#define NCH_  32     // S/64 chunks
#define SLOWSTRIDE (1544 * 512)   // fw_slow_w per-layer stride (floats)

typedef unsigned short u16;
typedef __attribute__((ext_vector_type(8))) short short8;
typedef __attribute__((ext_vector_type(4))) float f32x4;

__device__ __forceinline__ u16 f2bf(float x) {           // RNE fp32->bf16
  unsigned u = __builtin_bit_cast(unsigned, x);
  unsigned r = (u + 0x7FFFu + ((u >> 16) & 1u)) >> 16;
  return (u16)r;
}
__device__ __forceinline__ float bf2f(u16 v) {
  return __builtin_bit_cast(float, (unsigned)v << 16);
}
__device__ __forceinline__ void gload16(const void* g, void* l) {
  __builtin_amdgcn_global_load_lds(
      (const __attribute__((address_space(1))) unsigned int*)g,
      (__attribute__((address_space(3))) unsigned int*)l, 16, 0, 0);
}

// 64x64x64 product C[r][c] = sum_k F[r][k]*G[c][k], bf16 LDS operands.
template<int FS, int GS>
__device__ __forceinline__ void prod64(const u16* __restrict__ F,
                                       const u16* __restrict__ G,
                                       int wrow0, int lane, f32x4 acc[4])
{
  short8 f0 = *(const short8*)&F[(wrow0 + (lane & 15)) * FS + ((lane >> 4) * 8)];
  short8 f1 = *(const short8*)&F[(wrow0 + (lane & 15)) * FS + 32 + ((lane >> 4) * 8)];
  #pragma unroll
  for (int c0 = 0; c0 < 4; ++c0) {
    short8 g0 = *(const short8*)&G[(c0 * 16 + (lane & 15)) * GS + ((lane >> 4) * 8)];
    short8 g1 = *(const short8*)&G[(c0 * 16 + (lane & 15)) * GS + 32 + ((lane >> 4) * 8)];
    acc[c0] = __builtin_amdgcn_mfma_f32_16x16x32_bf16(f0, g0, acc[c0], 0, 0, 0);
    acc[c0] = __builtin_amdgcn_mfma_f32_16x16x32_bf16(f1, g1, acc[c0], 0, 0, 0);
  }
}

// ---------------------------------------------------------------------------
// bf16 GEMM: double-buffered global_load_lds staging (issue-early, one
// barrier/K-tile), both-sides swizzle, LDS-staged coalesced epilogue.
// TRANS: output written [S,B]->[B,S] transposed. QKVB: fused softmax/sigmoid.
// All M,N multiples of 128 (QN_ padded) -> no bounds checks.
// ---------------------------------------------------------------------------
template<bool BIAS, bool RELU, bool RES, bool OUTBF, bool TRANS, bool QKVB>
__global__ __launch_bounds__(256) void gemm_bf(
    const u16* __restrict__ A, const u16* __restrict__ W,
    const float* __restrict__ bias, const float* __restrict__ res,
    void* __restrict__ Cout, int M, int N, int K)
{
  __shared__ __align__(16) u16 SH[32768];   // 64KB: [As0|Bs0|As1|Bs1], 8192 u16 each
  const int tid = threadIdx.x, lane = tid & 63, wv = tid >> 6;
  const int bm = blockIdx.y * 128, bn = blockIdx.x * 128;
  const int wr = wv >> 1, wc = wv & 1;
  const int row16 = lane & 15, kg = lane >> 4;
  const int srow = lane >> 3;
  const int soff = ((lane & 7) * 16) ^ (srow << 4);

  f32x4 acc[4][4] = {};
  const int ktiles = K >> 6;

  auto STAGE = [&](int buf, int kt) {
    u16* As = &SH[buf * 16384];
    u16* Bs = &SH[buf * 16384 + 8192];
    #pragma unroll
    for (int i = 0; i < 4; ++i) {
      const int r = i * 32 + wv * 8;                          // wave-uniform
      const char* ga = (const char*)(A + (size_t)(bm + r + srow) * K + (size_t)kt * 64) + soff;
      gload16(ga, &As[r * 64]);
      const char* gw = (const char*)(W + (size_t)(bn + r + srow) * K + (size_t)kt * 64) + soff;
      gload16(gw, &Bs[r * 64]);
    }
  };

  STAGE(0, 0);
  __syncthreads();                 // buf0 ready
  int buf = 0;
  for (int kt = 0; kt < ktiles; ++kt) {
    if (kt + 1 < ktiles) STAGE(buf ^ 1, kt + 1);   // issue-early: overlaps MFMA below
    const u16* As = &SH[buf * 16384];
    const u16* Bs = &SH[buf * 16384 + 8192];
    #pragma unroll
    for (int kh = 0; kh < 2; ++kh) {
      const int fb = ((kh * 64 + kg * 16) ^ ((row16 & 7) << 4)) >> 1;
      short8 af[4], bf_[4];
      #pragma unroll
      for (int m = 0; m < 4; ++m)
        af[m] = *(const short8*)&As[(wr * 64 + m * 16 + row16) * 64 + fb];
      #pragma unroll
      for (int n = 0; n < 4; ++n)
        bf_[n] = *(const short8*)&Bs[(wc * 64 + n * 16 + row16) * 64 + fb];
      #pragma unroll
      for (int m = 0; m < 4; ++m)
        #pragma unroll
        for (int n = 0; n < 4; ++n)
          acc[m][n] = __builtin_amdgcn_mfma_f32_16x16x32_bf16(af[m], bf_[n], acc[m][n], 0, 0, 0);
    }
    __syncthreads();               // drains vmcnt(0): next buf landed; LDS reads done
    buf ^= 1;
  }

  if (QKVB) {
    const int span0 = bn + wc * 64;           // wave-uniform 64-col head span
    #pragma unroll
    for (int m = 0; m < 4; ++m) {
      #pragma unroll
      for (int j = 0; j < 4; ++j) {
        if (span0 < 1024) {                   // q or k: row softmax over 64 cols
          float v0 = acc[m][0][j], v1 = acc[m][1][j];
          float v2 = acc[m][2][j], v3 = acc[m][3][j];
          float mx = fmaxf(fmaxf(v0, v1), fmaxf(v2, v3));
          #pragma unroll
          for (int off = 1; off < 16; off <<= 1) mx = fmaxf(mx, __shfl_xor(mx, off));
          float e0 = __expf(v0 - mx), e1 = __expf(v1 - mx);
          float e2 = __expf(v2 - mx), e3 = __expf(v3 - mx);
          float s = (e0 + e1) + (e2 + e3);
          #pragma unroll
          for (int off = 1; off < 16; off <<= 1) s += __shfl_xor(s, off);
          float r = 1.f / s;
          acc[m][0][j] = e0 * r; acc[m][1][j] = e1 * r;
          acc[m][2][j] = e2 * r; acc[m][3][j] = e3 * r;
        } else if (span0 >= 1536) {           // beta cols: sigmoid
          #pragma unroll
          for (int n = 0; n < 4; ++n)
            acc[m][n][j] = 1.f / (1.f + __expf(-acc[m][n][j]));
        }
      }
    }
  }

  // LDS-staged epilogue: 2 passes of 64 rows (fp32), coalesced loads/stores.
  float* LD = (float*)SH;          // [64][132], 33.8KB
  #pragma unroll
  for (int p = 0; p < 2; ++p) {
    if (p) __syncthreads();        // pass-0 stores done before overwrite
    if (wr == p) {
      #pragma unroll
      for (int m = 0; m < 4; ++m)
        #pragma unroll
        for (int n = 0; n < 4; ++n)
          #pragma unroll
          for (int j = 0; j < 4; ++j)
            LD[(m * 16 + kg * 4 + j) * 132 + wc * 64 + n * 16 + row16] = acc[m][n][j];
    }
    __syncthreads();
    #pragma unroll
    for (int step = 0; step < 8; ++step) {
      int linear = step * 256 + tid;
      int row = linear >> 5, q = linear & 31;
      float4 v = *(const float4*)&LD[row * 132 + q * 4];
      const int grow = bm + p * 64 + row;
      const int gcol = bn + q * 4;
      if (BIAS) {
        float4 b4 = *(const float4*)&bias[gcol];
        v.x += b4.x; v.y += b4.y; v.z += b4.z; v.w += b4.w;
      }
      if (RES) {
        float4 r4 = *(const float4*)&res[(size_t)grow * N + gcol];
        v.x += r4.x; v.y += r4.y; v.z += r4.z; v.w += r4.w;
      }
      if (RELU) {
        v.x = fmaxf(v.x, 0.f); v.y = fmaxf(v.y, 0.f);
        v.z = fmaxf(v.z, 0.f); v.w = fmaxf(v.w, 0.f);
      }
      size_t gr = TRANS ? ((size_t)(grow & 7) * S_ + (grow >> 3)) : (size_t)grow;
      if (OUTBF) {
        uint2 pk;
        pk.x = (unsigned)f2bf(v.x) | ((unsigned)f2bf(v.y) << 16);
        pk.y = (unsigned)f2bf(v.z) | ((unsigned)f2bf(v.w) << 16);
        *(uint2*)&((u16*)Cout)[gr * N + gcol] = pk;
      } else {
        *(float4*)&((float*)Cout)[gr * N + gcol] = v;
      }
    }
  }
}

// ---------------------------------------------------------------------------
__global__ __launch_bounds__(256) void conv_w(const float* __restrict__ s,
                                              u16* __restrict__ d, int n, int npad)
{
  int i = blockIdx.x * 256 + threadIdx.x;
  if (i < npad) d[i] = (i < n) ? f2bf(s[i]) : (u16)0;
}

// slow_w reordered head-aligned: rows [q 512 | k 512 | v 512 | beta 8 | pad]
__global__ __launch_bounds__(256) void conv_slow(const float* __restrict__ s,
                                                 u16* __restrict__ d)
{
  int r = blockIdx.x;
  int src;
  if (r < 512)       src = (r >> 6) * 193 + (r & 63);
  else if (r < 1024) src = ((r - 512) >> 6) * 193 + 64 + (r & 63);
  else if (r < 1536) src = ((r - 1024) >> 6) * 193 + 128 + (r & 63);
  else if (r < 1544) src = (r - 1536) * 193 + 192;
  else               src = -1;
  for (int c = threadIdx.x; c < 512; c += 256)
    d[(size_t)r * 512 + c] = (src >= 0) ? f2bf(s[(size_t)src * 512 + c]) : (u16)0;
}

__global__ __launch_bounds__(64) void conv_x(const float* __restrict__ x,
                                             u16* __restrict__ xbf)
{
  size_t m = blockIdx.x;
  size_t s = m >> 3, b = m & 7;
  const float4* src = (const float4*)(x + (b * (size_t)S_ + s) * HID_);
  float4 v0 = src[threadIdx.x], v1 = src[64 + threadIdx.x];
  u16* dst = xbf + m * HID_;
  uint2 p0, p1;
  p0.x = (unsigned)f2bf(v0.x) | ((unsigned)f2bf(v0.y) << 16);
  p0.y = (unsigned)f2bf(v0.z) | ((unsigned)f2bf(v0.w) << 16);
  p1.x = (unsigned)f2bf(v1.x) | ((unsigned)f2bf(v1.y) << 16);
  p1.y = (unsigned)f2bf(v1.z) | ((unsigned)f2bf(v1.w) << 16);
  *(uint2*)&dst[threadIdx.x * 4] = p0;
  *(uint2*)&dst[256 + threadIdx.x * 4] = p1;
}

__global__ __launch_bounds__(64) void ln_bf(const float* __restrict__ x,
    const float* __restrict__ g, const float* __restrict__ bt,
    u16* __restrict__ o)
{
  size_t row = blockIdx.x;
  int lane = threadIdx.x;
  const float4* xr = (const float4*)(x + row * HID_);
  float4 v0 = xr[lane];
  float4 v1 = xr[64 + lane];
  float s  = v0.x + v0.y + v0.z + v0.w + v1.x + v1.y + v1.z + v1.w;
  float ss = v0.x*v0.x + v0.y*v0.y + v0.z*v0.z + v0.w*v0.w
           + v1.x*v1.x + v1.y*v1.y + v1.z*v1.z + v1.w*v1.w;
  #pragma unroll
  for (int off = 32; off; off >>= 1) {
    s  += __shfl_xor(s, off);
    ss += __shfl_xor(ss, off);
  }
  float mean = s * (1.f / HID_);
  float inv  = rsqrtf(ss * (1.f / HID_) - mean * mean + 1e-5f);
  const float4* gv = (const float4*)g;
  const float4* bv = (const float4*)bt;
  float4 g0 = gv[lane], g1 = gv[64 + lane];
  float4 b0 = bv[lane], b1 = bv[64 + lane];
  uint2 p0, p1;
  p0.x = (unsigned)f2bf((v0.x - mean) * inv * g0.x + b0.x)
       | ((unsigned)f2bf((v0.y - mean) * inv * g0.y + b0.y) << 16);
  p0.y = (unsigned)f2bf((v0.z - mean) * inv * g0.z + b0.z)
       | ((unsigned)f2bf((v0.w - mean) * inv * g0.w + b0.w) << 16);
  p1.x = (unsigned)f2bf((v1.x - mean) * inv * g1.x + b1.x)
       | ((unsigned)f2bf((v1.y - mean) * inv * g1.y + b1.y) << 16);
  p1.y = (unsigned)f2bf((v1.z - mean) * inv * g1.z + b1.z)
       | ((unsigned)f2bf((v1.w - mean) * inv * g1.w + b1.w) << 16);
  u16* ov = o + row * HID_;
  *(uint2*)&ov[lane * 4] = p0;
  *(uint2*)&ov[256 + lane * 4] = p1;
}

// ---------------------------------------------------------------------------
// Delta rule 3-phase (substitution structure, bf16 qkvb inputs). Unchanged.
// ---------------------------------------------------------------------------
__global__ __launch_bounds__(256, 2) void delta_p1(const u16* __restrict__ qf,
                                                   u16* __restrict__ MTg,
                                                   u16* __restrict__ Ng,
                                                   u16* __restrict__ CKg,
                                                   u16* __restrict__ U0Tg)
{
  __shared__ __align__(16) u16 Kb[64 * 72];
  __shared__ __align__(16) float Am[64][65];
  __shared__ __align__(16) float Uv[64][65];
  __shared__ __align__(16) float Uk[64][65];
  __shared__ __align__(16) u16 CKTb[64 * 72];
  __shared__ __align__(16) u16 U0Tb[64 * 72];
  __shared__ float bet[64];
  u16* KTb = (u16*)&Am[0][0];   // stride 88, aliased (Am dead post-solve)

  const int id5 = blockIdx.x, bh = id5 >> 5;
  const int b = bh & 7, h = bh >> 3, t0 = (id5 & 31) * 64;
  const int tid = threadIdx.x, lane = tid & 63, wv = tid >> 6;
  const int wid = wv, wrow0 = wv * 16;

  #pragma unroll
  for (int p = 0; p < 2; ++p) {
    int linear = p * 256 + tid, row = linear >> 3, seg = linear & 7;
    uint4 k4 = *(const uint4*)&qf[((size_t)(t0 + row) * B_ + b) * QN_ + 512 + h * 64 + seg * 8];
    *(short8*)&Kb[row * 72 + seg * 8] = __builtin_bit_cast(short8, k4);
  }
  if (tid < 64) bet[tid] = bf2f(qf[((size_t)(t0 + tid) * B_ + b) * QN_ + 1536 + h]);
  __syncthreads();

  {
    f32x4 a[4] = {};
    prod64<72, 72>(Kb, Kb, wrow0, lane, a);
    #pragma unroll
    for (int c0 = 0; c0 < 4; ++c0)
      #pragma unroll
      for (int j = 0; j < 4; ++j) {
        int row = wrow0 + (lane >> 4) * 4 + j, col = c0 * 16 + (lane & 15);
        Am[row][col] = bet[row] * a[c0][j];
      }
  }
  #pragma unroll
  for (int p = 0; p < 2; ++p) {
    int linear = p * 256 + tid, row = linear >> 3, seg = linear & 7;
    float bt_ = bet[row];
    uint4 v4 = *(const uint4*)&qf[((size_t)(t0 + row) * B_ + b) * QN_ + 1024 + h * 64 + seg * 8];
    short8 vs = __builtin_bit_cast(short8, v4);
    short8 ks = *(const short8*)&Kb[row * 72 + seg * 8];
    #pragma unroll
    for (int e = 0; e < 8; ++e) {
      Uv[row][seg * 8 + e] = bt_ * bf2f((u16)vs[e]);
      Uk[row][seg * 8 + e] = bt_ * bf2f((u16)ks[e]);
    }
  }
  __syncthreads();

  #pragma unroll 1
  for (int blk = 0; blk < 4; ++blk) {
    if (wid == blk) {
      const int r0 = blk * 16;
      float uv[16], uk[16];
      #pragma unroll
      for (int i = 0; i < 16; ++i) { uv[i] = Uv[r0 + i][lane]; uk[i] = Uk[r0 + i][lane]; }
      #pragma unroll
      for (int jj = 0; jj < 15; ++jj) {
        #pragma unroll
        for (int t = jj + 1; t < 16; ++t) {
          float a = Am[r0 + t][r0 + jj];
          uv[t] = fmaf(-a, uv[jj], uv[t]);
          uk[t] = fmaf(-a, uk[jj], uk[t]);
        }
      }
      #pragma unroll
      for (int i = 0; i < 16; ++i) { Uv[r0 + i][lane] = uv[i]; Uk[r0 + i][lane] = uk[i]; }
    }
    __syncthreads();
    if (wid > blk) {
      const int r0 = blk * 16, rw = wid * 16;
      float uv[16], uk[16];
      #pragma unroll
      for (int i = 0; i < 16; ++i) { uv[i] = Uv[rw + i][lane]; uk[i] = Uk[rw + i][lane]; }
      #pragma unroll
      for (int jj = 0; jj < 16; ++jj) {
        float sv = Uv[r0 + jj][lane], sk = Uk[r0 + jj][lane];
        #pragma unroll
        for (int i = 0; i < 16; ++i) {
          float a = Am[rw + i][r0 + jj];
          uv[i] = fmaf(-a, sv, uv[i]);
          uk[i] = fmaf(-a, sk, uk[i]);
        }
      }
      #pragma unroll
      for (int i = 0; i < 16; ++i) { Uv[rw + i][lane] = uv[i]; Uk[rw + i][lane] = uk[i]; }
    }
    __syncthreads();
  }

  const int prow = tid >> 2, pc0 = (tid & 3) * 16;
  const size_t mb = (size_t)id5 * 4096;
  {
    union { u16 u[16]; uint4 v[2]; } pk, pu;
    #pragma unroll
    for (int i = 0; i < 16; ++i) pk.u[i] = f2bf(Uk[prow][pc0 + i]);   // CK[t][d]
    #pragma unroll
    for (int i = 0; i < 16; ++i) pu.u[i] = f2bf(Uv[pc0 + i][prow]);   // U0T[d][t]
    *(uint4*)&CKg[mb + prow * 64 + pc0]      = pk.v[0];
    *(uint4*)&CKg[mb + prow * 64 + pc0 + 8]  = pk.v[1];
    *(uint4*)&U0Tg[mb + prow * 64 + pc0]     = pu.v[0];
    *(uint4*)&U0Tg[mb + prow * 64 + pc0 + 8] = pu.v[1];
    *(short8*)&U0Tb[prow * 72 + pc0]     = *(short8*)&pu.u[0];
    *(short8*)&U0Tb[prow * 72 + pc0 + 8] = *(short8*)&pu.u[8];
    #pragma unroll
    for (int i = 0; i < 16; ++i) CKTb[prow * 72 + pc0 + i] = f2bf(Uk[pc0 + i][prow]);
    #pragma unroll
    for (int i = 0; i < 16; ++i) KTb[prow * 88 + pc0 + i] = Kb[(pc0 + i) * 72 + prow];
  }
  __syncthreads();

  {
    f32x4 am[4] = {}, an[4] = {};
    prod64<88, 72>(KTb, CKTb, wrow0, lane, am);
    prod64<72, 88>(U0Tb, KTb, wrow0, lane, an);
    #pragma unroll
    for (int c0 = 0; c0 < 4; ++c0)
      #pragma unroll
      for (int j = 0; j < 4; ++j) {
        int row = wrow0 + (lane >> 4) * 4 + j, col = c0 * 16 + (lane & 15);
        MTg[mb + (size_t)row * 64 + col] = f2bf(am[c0][j]);
        Ng[mb + (size_t)row * 64 + col]  = f2bf(an[c0][j]);
      }
  }
}

__global__ __launch_bounds__(256, 1) void delta_p2(const u16* __restrict__ MTg,
                                                   const u16* __restrict__ Ng,
                                                   u16* __restrict__ Wsnap)
{
  __shared__ float Ws[64][65];
  __shared__ __align__(16) u16 Wbf[64 * 72];
  __shared__ __align__(16) u16 MTb[64 * 72];
  __shared__ __align__(16) u16 Nb[64 * 72];
  const int bh = blockIdx.x;
  const int tid = threadIdx.x, lane = tid & 63, wv = tid >> 6, wrow0 = wv * 16;
  const int prow = tid >> 2, pc0 = (tid & 3) * 16;

  for (int i = tid; i < 64 * 65; i += 256) (&Ws[0][0])[i] = 0.f;
  for (int i = tid; i < 64 * 72; i += 256) Wbf[i] = 0;
  __syncthreads();

  size_t base = (size_t)bh * NCH_ * 4096;
  uint4 rm0 = *(const uint4*)&MTg[base + prow * 64 + pc0];
  uint4 rm1 = *(const uint4*)&MTg[base + prow * 64 + pc0 + 8];
  uint4 rn0 = *(const uint4*)&Ng[base + prow * 64 + pc0];
  uint4 rn1 = *(const uint4*)&Ng[base + prow * 64 + pc0 + 8];

  for (int j = 0; j < NCH_; ++j) {
    *(short8*)&MTb[prow * 72 + pc0]     = __builtin_bit_cast(short8, rm0);
    *(short8*)&MTb[prow * 72 + pc0 + 8] = __builtin_bit_cast(short8, rm1);
    *(short8*)&Nb[prow * 72 + pc0]      = __builtin_bit_cast(short8, rn0);
    *(short8*)&Nb[prow * 72 + pc0 + 8]  = __builtin_bit_cast(short8, rn1);
    {
      size_t sb = base + (size_t)j * 4096;
      short8 w0 = *(const short8*)&Wbf[prow * 72 + pc0];
      short8 w1 = *(const short8*)&Wbf[prow * 72 + pc0 + 8];
      *(uint4*)&Wsnap[sb + prow * 64 + pc0]     = __builtin_bit_cast(uint4, w0);
      *(uint4*)&Wsnap[sb + prow * 64 + pc0 + 8] = __builtin_bit_cast(uint4, w1);
    }
    if (j + 1 < NCH_) {
      size_t nb2 = base + (size_t)(j + 1) * 4096;
      rm0 = *(const uint4*)&MTg[nb2 + prow * 64 + pc0];
      rm1 = *(const uint4*)&MTg[nb2 + prow * 64 + pc0 + 8];
      rn0 = *(const uint4*)&Ng[nb2 + prow * 64 + pc0];
      rn1 = *(const uint4*)&Ng[nb2 + prow * 64 + pc0 + 8];
    }
    __syncthreads();
    f32x4 a[4] = {};
    prod64<72, 72>(Wbf, MTb, wrow0, lane, a);
    #pragma unroll
    for (int c0 = 0; c0 < 4; ++c0)
      #pragma unroll
      for (int jj = 0; jj < 4; ++jj) {
        int row = wrow0 + (lane >> 4) * 4 + jj, col = c0 * 16 + (lane & 15);
        float w = Ws[row][col] + bf2f(Nb[row * 72 + col]) - a[c0][jj];
        Ws[row][col] = w;
        Wbf[row * 72 + col] = f2bf(w);
      }
    __syncthreads();
  }
}

__global__ __launch_bounds__(256, 2) void delta_p3(const u16* __restrict__ qf,
                                                   const u16* __restrict__ Wsnap,
                                                   const u16* __restrict__ CKg,
                                                   const u16* __restrict__ U0Tg,
                                                   u16* __restrict__ attnb)
{
  __shared__ __align__(16) u16 Qb[64 * 72];
  __shared__ __align__(16) u16 Kb[64 * 72];
  __shared__ __align__(16) u16 W0b[64 * 72];
  __shared__ __align__(16) u16 CKb[64 * 72];
  __shared__ __align__(16) u16 U0Tb[64 * 72];
  __shared__ __align__(16) u16 Gb[64 * 72];
  __shared__ __align__(16) u16 UTb[64 * 72];

  const int id5 = blockIdx.x, bh = id5 >> 5;
  const int b = bh & 7, h = bh >> 3, t0 = (id5 & 31) * 64;
  const int tid = threadIdx.x, lane = tid & 63, wv = tid >> 6, wrow0 = wv * 16;
  const int prow = tid >> 2, pc0 = (tid & 3) * 16;
  const size_t mb = (size_t)id5 * 4096;

  #pragma unroll
  for (int p = 0; p < 2; ++p) {
    int linear = p * 256 + tid, row = linear >> 3, seg = linear & 7;
    size_t gb = ((size_t)(t0 + row) * B_ + b) * QN_;
    uint4 q4 = *(const uint4*)&qf[gb + h * 64 + seg * 8];
    uint4 k4 = *(const uint4*)&qf[gb + 512 + h * 64 + seg * 8];
    uint4 w4 = *(const uint4*)&Wsnap[mb + (size_t)row * 64 + seg * 8];
    *(short8*)&Qb[row * 72 + seg * 8]  = __builtin_bit_cast(short8, q4);
    *(short8*)&Kb[row * 72 + seg * 8]  = __builtin_bit_cast(short8, k4);
    *(short8*)&W0b[row * 72 + seg * 8] = __builtin_bit_cast(short8, w4);
  }
  {
    uint4 c0v = *(const uint4*)&CKg[mb + prow * 64 + pc0];
    uint4 c1v = *(const uint4*)&CKg[mb + prow * 64 + pc0 + 8];
    uint4 u0v = *(const uint4*)&U0Tg[mb + prow * 64 + pc0];
    uint4 u1v = *(const uint4*)&U0Tg[mb + prow * 64 + pc0 + 8];
    *(short8*)&CKb[prow * 72 + pc0]      = __builtin_bit_cast(short8, c0v);
    *(short8*)&CKb[prow * 72 + pc0 + 8]  = __builtin_bit_cast(short8, c1v);
    *(short8*)&U0Tb[prow * 72 + pc0]     = __builtin_bit_cast(short8, u0v);
    *(short8*)&U0Tb[prow * 72 + pc0 + 8] = __builtin_bit_cast(short8, u1v);
  }
  __syncthreads();

  f32x4 ag[4] = {}, ac[4] = {}, ab[4] = {};
  prod64<72, 72>(Qb, Kb, wrow0, lane, ag);    // QK^T
  prod64<72, 72>(W0b, CKb, wrow0, lane, ac);  // (W0·CK^T)[d][t]
  prod64<72, 72>(Qb, W0b, wrow0, lane, ab);   // Q·W0^T

  #pragma unroll
  for (int c0 = 0; c0 < 4; ++c0)
    #pragma unroll
    for (int j = 0; j < 4; ++j) {
      int row = wrow0 + (lane >> 4) * 4 + j, col = c0 * 16 + (lane & 15);
      Gb[row * 72 + col]  = f2bf(col <= row ? ag[c0][j] : 0.f);
      UTb[row * 72 + col] = f2bf(bf2f(U0Tb[row * 72 + col]) - ac[c0][j]);
    }
  __syncthreads();

  prod64<72, 72>(Gb, UTb, wrow0, lane, ab);   // += G·U

  #pragma unroll
  for (int c0 = 0; c0 < 4; ++c0)
    #pragma unroll
    for (int j = 0; j < 4; ++j) {
      int row = wrow0 + (lane >> 4) * 4 + j, col = c0 * 16 + (lane & 15);
      attnb[((size_t)(t0 + row) * B_ + b) * HID_ + h * 64 + col] = f2bf(ab[c0][j]);
    }
}

// ---------------------------------------------------------------------------
extern "C" void kernel_launch(void* const* d_in, const int* in_sizes, int n_in,
                              void* d_out, int out_size, void* d_ws, size_t ws_size,
                              hipStream_t stream)
{
  const float* x        = (const float*)d_in[0];
  const float* ip_w     = (const float*)d_in[1];
  const float* ip_b     = (const float*)d_in[2];
  const float* fw_ln_g  = (const float*)d_in[3];
  const float* fw_ln_b  = (const float*)d_in[4];
  const float* fw_slow_w = (const float*)d_in[5];
  const float* fw_out_w  = (const float*)d_in[6];
  const float* ff_ln_g  = (const float*)d_in[7];
  const float* ff_ln_b  = (const float*)d_in[8];
  const float* ff_w1    = (const float*)d_in[9];
  const float* ff_b1    = (const float*)d_in[10];
  const float* ff_w2    = (const float*)d_in[11];
  const float* ff_b2    = (const float*)d_in[12];
  float* out = (float*)d_out;

  const int M = B_ * S_;  // 16384
  const size_t matN = (size_t)64 * NCH_ * 4096;   // 8.39M elems

  const size_t nIp = 512 * 512, nOut = 512 * 512;
  const size_t nSlow = (size_t)QN_ * 512;
  const size_t nW1 = (size_t)FF_ * 512, nW2 = (size_t)512 * FF_;
  const size_t nXbf = (size_t)M * HID_;
  const size_t poolElems = nIp + 2 * nSlow + 2 * nOut + nW1 + nW2 + nXbf + matN;

  size_t need = (size_t)M * HID_ * 4
              + ((size_t)M * QN_ + 2 * matN + poolElems) * 2;
  if (ws_size < need) return;

  float* cur   = (float*)d_ws;
  u16*   qkvbf = (u16*)(cur + (size_t)M * HID_);            // [M][1664] bf16
  u16*   attnSlot = qkvbf + (size_t)M * QN_;                // 2*matN u16
  u16*   MTg   = attnSlot;
  u16*   Ng    = MTg + matN;
  u16*   attnb = attnSlot;                                  // reuses MTg after p2
  u16*   CKg   = (u16*)out;
  u16*   U0Tg  = CKg + matN;
  u16*   tmpbf = (u16*)out;                                 // LN out; dead when CKg live
  u16*   hiddenb = qkvbf;                                   // FFN hidden (qkvbf+attn dead)

  u16* pool = attnSlot + 2 * matN;
  u16* ipwb   = pool;               pool += nIp;
  u16* slowb0 = pool;               pool += nSlow;
  u16* slowb1 = pool;               pool += nSlow;
  u16* outwb0 = pool;               pool += nOut;
  u16* outwb1 = pool;               pool += nOut;
  u16* w1b    = pool;               pool += nW1;
  u16* w2b    = pool;               pool += nW2;
  u16* Wsnap  = pool;               pool += matN;
  u16* xbf    = pool;

  dim3 blk(256);

  conv_w<<<(nIp + 255) / 256, blk, 0, stream>>>(ip_w, ipwb, nIp, nIp);
  conv_slow<<<QN_, blk, 0, stream>>>(fw_slow_w, slowb0);
  conv_slow<<<QN_, blk, 0, stream>>>(fw_slow_w + (size_t)SLOWSTRIDE, slowb1);
  conv_w<<<(nOut + 255) / 256, blk, 0, stream>>>(fw_out_w, outwb0, nOut, nOut);
  conv_w<<<(nOut + 255) / 256, blk, 0, stream>>>(fw_out_w + (size_t)512 * 512, outwb1, nOut, nOut);
  conv_w<<<(nW1 + 255) / 256, blk, 0, stream>>>(ff_w1, w1b, nW1, nW1);
  conv_w<<<(nW2 + 255) / 256, blk, 0, stream>>>(ff_w2, w2b, nW2, nW2);
  conv_x<<<M, 64, 0, stream>>>(x, xbf);

  gemm_bf<true, false, false, false, false, false><<<dim3(4, 128), blk, 0, stream>>>(
      xbf, ipwb, ip_b, nullptr, cur, M, HID_, HID_);

  for (int layer = 0; layer < 2; ++layer) {
    u16* slowb = layer ? slowb1 : slowb0;
    u16* outwb = layer ? outwb1 : outwb0;

    ln_bf<<<M, 64, 0, stream>>>(cur, fw_ln_g + layer * HID_, fw_ln_b + layer * HID_, tmpbf);
    gemm_bf<false, false, false, true, false, true><<<dim3(13, 128), blk, 0, stream>>>(
        tmpbf, slowb, nullptr, nullptr, qkvbf, M, QN_, HID_);
    delta_p1<<<64 * NCH_, 256, 0, stream>>>(qkvbf, MTg, Ng, CKg, U0Tg);
    delta_p2<<<64, 256, 0, stream>>>(MTg, Ng, Wsnap);
    delta_p3<<<64 * NCH_, 256, 0, stream>>>(qkvbf, Wsnap, CKg, U0Tg, attnb);
    if (layer == 0) {
      gemm_bf<false, false, true, false, false, false><<<dim3(4, 128), blk, 0, stream>>>(
          attnb, outwb, nullptr, cur, cur, M, HID_, HID_);
      ln_bf<<<M, 64, 0, stream>>>(cur, ff_ln_g, ff_ln_b, tmpbf);
      gemm_bf<true, true, false, true, false, false><<<dim3(16, 128), blk, 0, stream>>>(
          tmpbf, w1b, ff_b1, nullptr, hiddenb, M, FF_, HID_);
      gemm_bf<true, false, true, false, false, false><<<dim3(4, 128), blk, 0, stream>>>(
          hiddenb, w2b, ff_b2, cur, cur, M, HID_, FF_);
    } else {
      // final out-proj writes [B,S,512] directly (fused transpose)
      gemm_bf<false, false, true, false, true, false><<<dim3(4, 128), blk, 0, stream>>>(
          attnb, outwb, nullptr, cur, out, M, HID_, HID_);
    }
  }
}

// Round 10
// 556.472 us; speedup vs baseline: 1.3359x; 1.0065x over previous
//
#include <hip/hip_runtime.h>
#include <hip/hip_bf16.h>

#define B_    8
#define S_    2048
#define HID_  512
#define H_    8
#define D_    64
#define FF_   2048
#define QN_   1664   // padded qkvb width: q 512 | k 512 | v 512 | beta 8 (pad 128)
#define NCH_  32     // S/64 chunks
#define SLOWSTRIDE (1544 * 512)   // fw_slow_w per-layer stride (floats)

typedef unsigned short u16;
typedef __attribute__((ext_vector_type(8))) short short8;
typedef __attribute__((ext_vector_type(4))) float f32x4;

__device__ __forceinline__ u16 f2bf(float x) {           // RNE fp32->bf16
  unsigned u = __builtin_bit_cast(unsigned, x);
  unsigned r = (u + 0x7FFFu + ((u >> 16) & 1u)) >> 16;
  return (u16)r;
}
__device__ __forceinline__ float bf2f(u16 v) {
  return __builtin_bit_cast(float, (unsigned)v << 16);
}
__device__ __forceinline__ void gload16(const void* g, void* l) {
  __builtin_amdgcn_global_load_lds(
      (const __attribute__((address_space(1))) unsigned int*)g,
      (__attribute__((address_space(3))) unsigned int*)l, 16, 0, 0);
}

// 64x64x64 product C[r][c] = sum_k F[r][k]*G[c][k], bf16 LDS operands.
template<int FS, int GS>
__device__ __forceinline__ void prod64(const u16* __restrict__ F,
                                       const u16* __restrict__ G,
                                       int wrow0, int lane, f32x4 acc[4])
{
  short8 f0 = *(const short8*)&F[(wrow0 + (lane & 15)) * FS + ((lane >> 4) * 8)];
  short8 f1 = *(const short8*)&F[(wrow0 + (lane & 15)) * FS + 32 + ((lane >> 4) * 8)];
  #pragma unroll
  for (int c0 = 0; c0 < 4; ++c0) {
    short8 g0 = *(const short8*)&G[(c0 * 16 + (lane & 15)) * GS + ((lane >> 4) * 8)];
    short8 g1 = *(const short8*)&G[(c0 * 16 + (lane & 15)) * GS + 32 + ((lane >> 4) * 8)];
    acc[c0] = __builtin_amdgcn_mfma_f32_16x16x32_bf16(f0, g0, acc[c0], 0, 0, 0);
    acc[c0] = __builtin_amdgcn_mfma_f32_16x16x32_bf16(f1, g1, acc[c0], 0, 0, 0);
  }
}

// ---------------------------------------------------------------------------
// bf16 GEMM: BK=32 double-buffered global_load_lds staging (32KB LDS ->
// 4-5 blocks/CU), both-sides swizzle, 4-pass LDS-staged coalesced epilogue.
// TRANS: output written [S,B]->[B,S] transposed. QKVB: fused softmax/sigmoid.
// All M,N multiples of 128, K multiple of 32 -> no bounds checks.
// ---------------------------------------------------------------------------
template<bool BIAS, bool RELU, bool RES, bool OUTBF, bool TRANS, bool QKVB>
__global__ __launch_bounds__(256, 4) void gemm_bf(
    const u16* __restrict__ A, const u16* __restrict__ W,
    const float* __restrict__ bias, const float* __restrict__ res,
    void* __restrict__ Cout, int M, int N, int K)
{
  __shared__ __align__(16) u16 SH[16384];   // 32KB: [As0|Bs0|As1|Bs1], 4096 u16 each
  const int tid = threadIdx.x, lane = tid & 63, wv = tid >> 6;
  const int bm = blockIdx.y * 128, bn = blockIdx.x * 128;
  const int wr = wv >> 1, wc = wv & 1;
  const int row16 = lane & 15, kg = lane >> 4;
  const int srow = lane >> 2;                      // 0..15: row within a gload call
  const int ssoff = ((lane & 3) ^ (srow & 3)) * 16; // pre-swizzled 16B source slot

  f32x4 acc[4][4] = {};
  const int ktiles = K >> 5;

  auto STAGE = [&](int buf, int kt) {
    u16* As = &SH[buf * 8192];
    u16* Bs = &SH[buf * 8192 + 4096];
    #pragma unroll
    for (int i = 0; i < 2; ++i) {
      const int r = i * 64 + wv * 16;              // wave-uniform row base
      const char* ga = (const char*)(A + (size_t)(bm + r + srow) * K + (size_t)kt * 32) + ssoff;
      gload16(ga, &As[r * 32]);
      const char* gw = (const char*)(W + (size_t)(bn + r + srow) * K + (size_t)kt * 32) + ssoff;
      gload16(gw, &Bs[r * 32]);
    }
  };

  STAGE(0, 0);
  __syncthreads();                 // buf0 ready
  int buf = 0;
  for (int kt = 0; kt < ktiles; ++kt) {
    if (kt + 1 < ktiles) STAGE(buf ^ 1, kt + 1);   // issue-early: overlaps MFMA
    const u16* As = &SH[buf * 8192];
    const u16* Bs = &SH[buf * 8192 + 4096];
    short8 af[4], bf_[4];
    #pragma unroll
    for (int m = 0; m < 4; ++m) {
      const int lrow = wr * 64 + m * 16 + row16;
      af[m] = *(const short8*)&As[lrow * 32 + (kg ^ (lrow & 3)) * 8];
    }
    #pragma unroll
    for (int n = 0; n < 4; ++n) {
      const int lrow = wc * 64 + n * 16 + row16;
      bf_[n] = *(const short8*)&Bs[lrow * 32 + (kg ^ (lrow & 3)) * 8];
    }
    #pragma unroll
    for (int m = 0; m < 4; ++m)
      #pragma unroll
      for (int n = 0; n < 4; ++n)
        acc[m][n] = __builtin_amdgcn_mfma_f32_16x16x32_bf16(af[m], bf_[n], acc[m][n], 0, 0, 0);
    __syncthreads();               // next buf landed; this buf's reads done
    buf ^= 1;
  }

  if (QKVB) {
    const int span0 = bn + wc * 64;           // wave-uniform 64-col head span
    #pragma unroll
    for (int m = 0; m < 4; ++m) {
      #pragma unroll
      for (int j = 0; j < 4; ++j) {
        if (span0 < 1024) {                   // q or k: row softmax over 64 cols
          float v0 = acc[m][0][j], v1 = acc[m][1][j];
          float v2 = acc[m][2][j], v3 = acc[m][3][j];
          float mx = fmaxf(fmaxf(v0, v1), fmaxf(v2, v3));
          #pragma unroll
          for (int off = 1; off < 16; off <<= 1) mx = fmaxf(mx, __shfl_xor(mx, off));
          float e0 = __expf(v0 - mx), e1 = __expf(v1 - mx);
          float e2 = __expf(v2 - mx), e3 = __expf(v3 - mx);
          float s = (e0 + e1) + (e2 + e3);
          #pragma unroll
          for (int off = 1; off < 16; off <<= 1) s += __shfl_xor(s, off);
          float r = 1.f / s;
          acc[m][0][j] = e0 * r; acc[m][1][j] = e1 * r;
          acc[m][2][j] = e2 * r; acc[m][3][j] = e3 * r;
        } else if (span0 >= 1536) {           // beta cols: sigmoid
          #pragma unroll
          for (int n = 0; n < 4; ++n)
            acc[m][n][j] = 1.f / (1.f + __expf(-acc[m][n][j]));
        }
      }
    }
  }

  // 4-pass LDS-staged epilogue: 32 rows/pass (fp32 [32][132] = 16.9KB < 32KB)
  float* LD = (float*)SH;
  #pragma unroll
  for (int p = 0; p < 4; ++p) {
    if (p) __syncthreads();        // previous pass stores done before overwrite
    if (wr == (p >> 1)) {
      #pragma unroll
      for (int mm = 0; mm < 2; ++mm) {
        const int m = (p & 1) * 2 + mm;
        #pragma unroll
        for (int n = 0; n < 4; ++n)
          #pragma unroll
          for (int j = 0; j < 4; ++j)
            LD[(mm * 16 + kg * 4 + j) * 132 + wc * 64 + n * 16 + row16] = acc[m][n][j];
      }
    }
    __syncthreads();
    #pragma unroll
    for (int step = 0; step < 4; ++step) {
      int linear = step * 256 + tid;           // 1024 float4 = 32 rows x 128 cols
      int row = linear >> 5, q = linear & 31;
      float4 v = *(const float4*)&LD[row * 132 + q * 4];
      const int grow = bm + p * 32 + row;
      const int gcol = bn + q * 4;
      if (BIAS) {
        float4 b4 = *(const float4*)&bias[gcol];
        v.x += b4.x; v.y += b4.y; v.z += b4.z; v.w += b4.w;
      }
      if (RES) {
        float4 r4 = *(const float4*)&res[(size_t)grow * N + gcol];
        v.x += r4.x; v.y += r4.y; v.z += r4.z; v.w += r4.w;
      }
      if (RELU) {
        v.x = fmaxf(v.x, 0.f); v.y = fmaxf(v.y, 0.f);
        v.z = fmaxf(v.z, 0.f); v.w = fmaxf(v.w, 0.f);
      }
      size_t gr = TRANS ? ((size_t)(grow & 7) * S_ + (grow >> 3)) : (size_t)grow;
      if (OUTBF) {
        uint2 pk;
        pk.x = (unsigned)f2bf(v.x) | ((unsigned)f2bf(v.y) << 16);
        pk.y = (unsigned)f2bf(v.z) | ((unsigned)f2bf(v.w) << 16);
        *(uint2*)&((u16*)Cout)[gr * N + gcol] = pk;
      } else {
        *(float4*)&((float*)Cout)[gr * N + gcol] = v;
      }
    }
  }
}

// ---------------------------------------------------------------------------
__global__ __launch_bounds__(256) void conv_w(const float* __restrict__ s,
                                              u16* __restrict__ d, int n, int npad)
{
  int i = blockIdx.x * 256 + threadIdx.x;
  if (i < npad) d[i] = (i < n) ? f2bf(s[i]) : (u16)0;
}

// slow_w reordered head-aligned: rows [q 512 | k 512 | v 512 | beta 8 | pad]
__global__ __launch_bounds__(256) void conv_slow(const float* __restrict__ s,
                                                 u16* __restrict__ d)
{
  int r = blockIdx.x;
  int src;
  if (r < 512)       src = (r >> 6) * 193 + (r & 63);
  else if (r < 1024) src = ((r - 512) >> 6) * 193 + 64 + (r & 63);
  else if (r < 1536) src = ((r - 1024) >> 6) * 193 + 128 + (r & 63);
  else if (r < 1544) src = (r - 1536) * 193 + 192;
  else               src = -1;
  for (int c = threadIdx.x; c < 512; c += 256)
    d[(size_t)r * 512 + c] = (src >= 0) ? f2bf(s[(size_t)src * 512 + c]) : (u16)0;
}

__global__ __launch_bounds__(64) void conv_x(const float* __restrict__ x,
                                             u16* __restrict__ xbf)
{
  size_t m = blockIdx.x;
  size_t s = m >> 3, b = m & 7;
  const float4* src = (const float4*)(x + (b * (size_t)S_ + s) * HID_);
  float4 v0 = src[threadIdx.x], v1 = src[64 + threadIdx.x];
  u16* dst = xbf + m * HID_;
  uint2 p0, p1;
  p0.x = (unsigned)f2bf(v0.x) | ((unsigned)f2bf(v0.y) << 16);
  p0.y = (unsigned)f2bf(v0.z) | ((unsigned)f2bf(v0.w) << 16);
  p1.x = (unsigned)f2bf(v1.x) | ((unsigned)f2bf(v1.y) << 16);
  p1.y = (unsigned)f2bf(v1.z) | ((unsigned)f2bf(v1.w) << 16);
  *(uint2*)&dst[threadIdx.x * 4] = p0;
  *(uint2*)&dst[256 + threadIdx.x * 4] = p1;
}

__global__ __launch_bounds__(64) void ln_bf(const float* __restrict__ x,
    const float* __restrict__ g, const float* __restrict__ bt,
    u16* __restrict__ o)
{
  size_t row = blockIdx.x;
  int lane = threadIdx.x;
  const float4* xr = (const float4*)(x + row * HID_);
  float4 v0 = xr[lane];
  float4 v1 = xr[64 + lane];
  float s  = v0.x + v0.y + v0.z + v0.w + v1.x + v1.y + v1.z + v1.w;
  float ss = v0.x*v0.x + v0.y*v0.y + v0.z*v0.z + v0.w*v0.w
           + v1.x*v1.x + v1.y*v1.y + v1.z*v1.z + v1.w*v1.w;
  #pragma unroll
  for (int off = 32; off; off >>= 1) {
    s  += __shfl_xor(s, off);
    ss += __shfl_xor(ss, off);
  }
  float mean = s * (1.f / HID_);
  float inv  = rsqrtf(ss * (1.f / HID_) - mean * mean + 1e-5f);
  const float4* gv = (const float4*)g;
  const float4* bv = (const float4*)bt;
  float4 g0 = gv[lane], g1 = gv[64 + lane];
  float4 b0 = bv[lane], b1 = bv[64 + lane];
  uint2 p0, p1;
  p0.x = (unsigned)f2bf((v0.x - mean) * inv * g0.x + b0.x)
       | ((unsigned)f2bf((v0.y - mean) * inv * g0.y + b0.y) << 16);
  p0.y = (unsigned)f2bf((v0.z - mean) * inv * g0.z + b0.z)
       | ((unsigned)f2bf((v0.w - mean) * inv * g0.w + b0.w) << 16);
  p1.x = (unsigned)f2bf((v1.x - mean) * inv * g1.x + b1.x)
       | ((unsigned)f2bf((v1.y - mean) * inv * g1.y + b1.y) << 16);
  p1.y = (unsigned)f2bf((v1.z - mean) * inv * g1.z + b1.z)
       | ((unsigned)f2bf((v1.w - mean) * inv * g1.w + b1.w) << 16);
  u16* ov = o + row * HID_;
  *(uint2*)&ov[lane * 4] = p0;
  *(uint2*)&ov[256 + lane * 4] = p1;
}

// ---------------------------------------------------------------------------
// Delta rule 3-phase (substitution structure, bf16 qkvb inputs). Unchanged.
// ---------------------------------------------------------------------------
__global__ __launch_bounds__(256, 2) void delta_p1(const u16* __restrict__ qf,
                                                   u16* __restrict__ MTg,
                                                   u16* __restrict__ Ng,
                                                   u16* __restrict__ CKg,
                                                   u16* __restrict__ U0Tg)
{
  __shared__ __align__(16) u16 Kb[64 * 72];
  __shared__ __align__(16) float Am[64][65];
  __shared__ __align__(16) float Uv[64][65];
  __shared__ __align__(16) float Uk[64][65];
  __shared__ __align__(16) u16 CKTb[64 * 72];
  __shared__ __align__(16) u16 U0Tb[64 * 72];
  __shared__ float bet[64];
  u16* KTb = (u16*)&Am[0][0];   // stride 88, aliased (Am dead post-solve)

  const int id5 = blockIdx.x, bh = id5 >> 5;
  const int b = bh & 7, h = bh >> 3, t0 = (id5 & 31) * 64;
  const int tid = threadIdx.x, lane = tid & 63, wv = tid >> 6;
  const int wid = wv, wrow0 = wv * 16;

  #pragma unroll
  for (int p = 0; p < 2; ++p) {
    int linear = p * 256 + tid, row = linear >> 3, seg = linear & 7;
    uint4 k4 = *(const uint4*)&qf[((size_t)(t0 + row) * B_ + b) * QN_ + 512 + h * 64 + seg * 8];
    *(short8*)&Kb[row * 72 + seg * 8] = __builtin_bit_cast(short8, k4);
  }
  if (tid < 64) bet[tid] = bf2f(qf[((size_t)(t0 + tid) * B_ + b) * QN_ + 1536 + h]);
  __syncthreads();

  {
    f32x4 a[4] = {};
    prod64<72, 72>(Kb, Kb, wrow0, lane, a);
    #pragma unroll
    for (int c0 = 0; c0 < 4; ++c0)
      #pragma unroll
      for (int j = 0; j < 4; ++j) {
        int row = wrow0 + (lane >> 4) * 4 + j, col = c0 * 16 + (lane & 15);
        Am[row][col] = bet[row] * a[c0][j];
      }
  }
  #pragma unroll
  for (int p = 0; p < 2; ++p) {
    int linear = p * 256 + tid, row = linear >> 3, seg = linear & 7;
    float bt_ = bet[row];
    uint4 v4 = *(const uint4*)&qf[((size_t)(t0 + row) * B_ + b) * QN_ + 1024 + h * 64 + seg * 8];
    short8 vs = __builtin_bit_cast(short8, v4);
    short8 ks = *(const short8*)&Kb[row * 72 + seg * 8];
    #pragma unroll
    for (int e = 0; e < 8; ++e) {
      Uv[row][seg * 8 + e] = bt_ * bf2f((u16)vs[e]);
      Uk[row][seg * 8 + e] = bt_ * bf2f((u16)ks[e]);
    }
  }
  __syncthreads();

  #pragma unroll 1
  for (int blk = 0; blk < 4; ++blk) {
    if (wid == blk) {
      const int r0 = blk * 16;
      float uv[16], uk[16];
      #pragma unroll
      for (int i = 0; i < 16; ++i) { uv[i] = Uv[r0 + i][lane]; uk[i] = Uk[r0 + i][lane]; }
      #pragma unroll
      for (int jj = 0; jj < 15; ++jj) {
        #pragma unroll
        for (int t = jj + 1; t < 16; ++t) {
          float a = Am[r0 + t][r0 + jj];
          uv[t] = fmaf(-a, uv[jj], uv[t]);
          uk[t] = fmaf(-a, uk[jj], uk[t]);
        }
      }
      #pragma unroll
      for (int i = 0; i < 16; ++i) { Uv[r0 + i][lane] = uv[i]; Uk[r0 + i][lane] = uk[i]; }
    }
    __syncthreads();
    if (wid > blk) {
      const int r0 = blk * 16, rw = wid * 16;
      float uv[16], uk[16];
      #pragma unroll
      for (int i = 0; i < 16; ++i) { uv[i] = Uv[rw + i][lane]; uk[i] = Uk[rw + i][lane]; }
      #pragma unroll
      for (int jj = 0; jj < 16; ++jj) {
        float sv = Uv[r0 + jj][lane], sk = Uk[r0 + jj][lane];
        #pragma unroll
        for (int i = 0; i < 16; ++i) {
          float a = Am[rw + i][r0 + jj];
          uv[i] = fmaf(-a, sv, uv[i]);
          uk[i] = fmaf(-a, sk, uk[i]);
        }
      }
      #pragma unroll
      for (int i = 0; i < 16; ++i) { Uv[rw + i][lane] = uv[i]; Uk[rw + i][lane] = uk[i]; }
    }
    __syncthreads();
  }

  const int prow = tid >> 2, pc0 = (tid & 3) * 16;
  const size_t mb = (size_t)id5 * 4096;
  {
    union { u16 u[16]; uint4 v[2]; } pk, pu;
    #pragma unroll
    for (int i = 0; i < 16; ++i) pk.u[i] = f2bf(Uk[prow][pc0 + i]);   // CK[t][d]
    #pragma unroll
    for (int i = 0; i < 16; ++i) pu.u[i] = f2bf(Uv[pc0 + i][prow]);   // U0T[d][t]
    *(uint4*)&CKg[mb + prow * 64 + pc0]      = pk.v[0];
    *(uint4*)&CKg[mb + prow * 64 + pc0 + 8]  = pk.v[1];
    *(uint4*)&U0Tg[mb + prow * 64 + pc0]     = pu.v[0];
    *(uint4*)&U0Tg[mb + prow * 64 + pc0 + 8] = pu.v[1];
    *(short8*)&U0Tb[prow * 72 + pc0]     = *(short8*)&pu.u[0];
    *(short8*)&U0Tb[prow * 72 + pc0 + 8] = *(short8*)&pu.u[8];
    #pragma unroll
    for (int i = 0; i < 16; ++i) CKTb[prow * 72 + pc0 + i] = f2bf(Uk[pc0 + i][prow]);
    #pragma unroll
    for (int i = 0; i < 16; ++i) KTb[prow * 88 + pc0 + i] = Kb[(pc0 + i) * 72 + prow];
  }
  __syncthreads();

  {
    f32x4 am[4] = {}, an[4] = {};
    prod64<88, 72>(KTb, CKTb, wrow0, lane, am);
    prod64<72, 88>(U0Tb, KTb, wrow0, lane, an);
    #pragma unroll
    for (int c0 = 0; c0 < 4; ++c0)
      #pragma unroll
      for (int j = 0; j < 4; ++j) {
        int row = wrow0 + (lane >> 4) * 4 + j, col = c0 * 16 + (lane & 15);
        MTg[mb + (size_t)row * 64 + col] = f2bf(am[c0][j]);
        Ng[mb + (size_t)row * 64 + col]  = f2bf(an[c0][j]);
      }
  }
}

__global__ __launch_bounds__(256, 1) void delta_p2(const u16* __restrict__ MTg,
                                                   const u16* __restrict__ Ng,
                                                   u16* __restrict__ Wsnap)
{
  __shared__ float Ws[64][65];
  __shared__ __align__(16) u16 Wbf[64 * 72];
  __shared__ __align__(16) u16 MTb[64 * 72];
  __shared__ __align__(16) u16 Nb[64 * 72];
  const int bh = blockIdx.x;
  const int tid = threadIdx.x, lane = tid & 63, wv = tid >> 6, wrow0 = wv * 16;
  const int prow = tid >> 2, pc0 = (tid & 3) * 16;

  for (int i = tid; i < 64 * 65; i += 256) (&Ws[0][0])[i] = 0.f;
  for (int i = tid; i < 64 * 72; i += 256) Wbf[i] = 0;
  __syncthreads();

  size_t base = (size_t)bh * NCH_ * 4096;
  uint4 rm0 = *(const uint4*)&MTg[base + prow * 64 + pc0];
  uint4 rm1 = *(const uint4*)&MTg[base + prow * 64 + pc0 + 8];
  uint4 rn0 = *(const uint4*)&Ng[base + prow * 64 + pc0];
  uint4 rn1 = *(const uint4*)&Ng[base + prow * 64 + pc0 + 8];

  for (int j = 0; j < NCH_; ++j) {
    *(short8*)&MTb[prow * 72 + pc0]     = __builtin_bit_cast(short8, rm0);
    *(short8*)&MTb[prow * 72 + pc0 + 8] = __builtin_bit_cast(short8, rm1);
    *(short8*)&Nb[prow * 72 + pc0]      = __builtin_bit_cast(short8, rn0);
    *(short8*)&Nb[prow * 72 + pc0 + 8]  = __builtin_bit_cast(short8, rn1);
    {
      size_t sb = base + (size_t)j * 4096;
      short8 w0 = *(const short8*)&Wbf[prow * 72 + pc0];
      short8 w1 = *(const short8*)&Wbf[prow * 72 + pc0 + 8];
      *(uint4*)&Wsnap[sb + prow * 64 + pc0]     = __builtin_bit_cast(uint4, w0);
      *(uint4*)&Wsnap[sb + prow * 64 + pc0 + 8] = __builtin_bit_cast(uint4, w1);
    }
    if (j + 1 < NCH_) {
      size_t nb2 = base + (size_t)(j + 1) * 4096;
      rm0 = *(const uint4*)&MTg[nb2 + prow * 64 + pc0];
      rm1 = *(const uint4*)&MTg[nb2 + prow * 64 + pc0 + 8];
      rn0 = *(const uint4*)&Ng[nb2 + prow * 64 + pc0];
      rn1 = *(const uint4*)&Ng[nb2 + prow * 64 + pc0 + 8];
    }
    __syncthreads();
    f32x4 a[4] = {};
    prod64<72, 72>(Wbf, MTb, wrow0, lane, a);
    #pragma unroll
    for (int c0 = 0; c0 < 4; ++c0)
      #pragma unroll
      for (int jj = 0; jj < 4; ++jj) {
        int row = wrow0 + (lane >> 4) * 4 + jj, col = c0 * 16 + (lane & 15);
        float w = Ws[row][col] + bf2f(Nb[row * 72 + col]) - a[c0][jj];
        Ws[row][col] = w;
        Wbf[row * 72 + col] = f2bf(w);
      }
    __syncthreads();
  }
}

__global__ __launch_bounds__(256, 2) void delta_p3(const u16* __restrict__ qf,
                                                   const u16* __restrict__ Wsnap,
                                                   const u16* __restrict__ CKg,
                                                   const u16* __restrict__ U0Tg,
                                                   u16* __restrict__ attnb)
{
  __shared__ __align__(16) u16 Qb[64 * 72];
  __shared__ __align__(16) u16 Kb[64 * 72];
  __shared__ __align__(16) u16 W0b[64 * 72];
  __shared__ __align__(16) u16 CKb[64 * 72];
  __shared__ __align__(16) u16 U0Tb[64 * 72];
  __shared__ __align__(16) u16 Gb[64 * 72];
  __shared__ __align__(16) u16 UTb[64 * 72];

  const int id5 = blockIdx.x, bh = id5 >> 5;
  const int b = bh & 7, h = bh >> 3, t0 = (id5 & 31) * 64;
  const int tid = threadIdx.x, lane = tid & 63, wv = tid >> 6, wrow0 = wv * 16;
  const int prow = tid >> 2, pc0 = (tid & 3) * 16;
  const size_t mb = (size_t)id5 * 4096;

  #pragma unroll
  for (int p = 0; p < 2; ++p) {
    int linear = p * 256 + tid, row = linear >> 3, seg = linear & 7;
    size_t gb = ((size_t)(t0 + row) * B_ + b) * QN_;
    uint4 q4 = *(const uint4*)&qf[gb + h * 64 + seg * 8];
    uint4 k4 = *(const uint4*)&qf[gb + 512 + h * 64 + seg * 8];
    uint4 w4 = *(const uint4*)&Wsnap[mb + (size_t)row * 64 + seg * 8];
    *(short8*)&Qb[row * 72 + seg * 8]  = __builtin_bit_cast(short8, q4);
    *(short8*)&Kb[row * 72 + seg * 8]  = __builtin_bit_cast(short8, k4);
    *(short8*)&W0b[row * 72 + seg * 8] = __builtin_bit_cast(short8, w4);
  }
  {
    uint4 c0v = *(const uint4*)&CKg[mb + prow * 64 + pc0];
    uint4 c1v = *(const uint4*)&CKg[mb + prow * 64 + pc0 + 8];
    uint4 u0v = *(const uint4*)&U0Tg[mb + prow * 64 + pc0];
    uint4 u1v = *(const uint4*)&U0Tg[mb + prow * 64 + pc0 + 8];
    *(short8*)&CKb[prow * 72 + pc0]      = __builtin_bit_cast(short8, c0v);
    *(short8*)&CKb[prow * 72 + pc0 + 8]  = __builtin_bit_cast(short8, c1v);
    *(short8*)&U0Tb[prow * 72 + pc0]     = __builtin_bit_cast(short8, u0v);
    *(short8*)&U0Tb[prow * 72 + pc0 + 8] = __builtin_bit_cast(short8, u1v);
  }
  __syncthreads();

  f32x4 ag[4] = {}, ac[4] = {}, ab[4] = {};
  prod64<72, 72>(Qb, Kb, wrow0, lane, ag);    // QK^T
  prod64<72, 72>(W0b, CKb, wrow0, lane, ac);  // (W0·CK^T)[d][t]
  prod64<72, 72>(Qb, W0b, wrow0, lane, ab);   // Q·W0^T

  #pragma unroll
  for (int c0 = 0; c0 < 4; ++c0)
    #pragma unroll
    for (int j = 0; j < 4; ++j) {
      int row = wrow0 + (lane >> 4) * 4 + j, col = c0 * 16 + (lane & 15);
      Gb[row * 72 + col]  = f2bf(col <= row ? ag[c0][j] : 0.f);
      UTb[row * 72 + col] = f2bf(bf2f(U0Tb[row * 72 + col]) - ac[c0][j]);
    }
  __syncthreads();

  prod64<72, 72>(Gb, UTb, wrow0, lane, ab);   // += G·U

  #pragma unroll
  for (int c0 = 0; c0 < 4; ++c0)
    #pragma unroll
    for (int j = 0; j < 4; ++j) {
      int row = wrow0 + (lane >> 4) * 4 + j, col = c0 * 16 + (lane & 15);
      attnb[((size_t)(t0 + row) * B_ + b) * HID_ + h * 64 + col] = f2bf(ab[c0][j]);
    }
}

// ---------------------------------------------------------------------------
extern "C" void kernel_launch(void* const* d_in, const int* in_sizes, int n_in,
                              void* d_out, int out_size, void* d_ws, size_t ws_size,
                              hipStream_t stream)
{
  const float* x        = (const float*)d_in[0];
  const float* ip_w     = (const float*)d_in[1];
  const float* ip_b     = (const float*)d_in[2];
  const float* fw_ln_g  = (const float*)d_in[3];
  const float* fw_ln_b  = (const float*)d_in[4];
  const float* fw_slow_w = (const float*)d_in[5];
  const float* fw_out_w  = (const float*)d_in[6];
  const float* ff_ln_g  = (const float*)d_in[7];
  const float* ff_ln_b  = (const float*)d_in[8];
  const float* ff_w1    = (const float*)d_in[9];
  const float* ff_b1    = (const float*)d_in[10];
  const float* ff_w2    = (const float*)d_in[11];
  const float* ff_b2    = (const float*)d_in[12];
  float* out = (float*)d_out;

  const int M = B_ * S_;  // 16384
  const size_t matN = (size_t)64 * NCH_ * 4096;   // 8.39M elems

  const size_t nIp = 512 * 512, nOut = 512 * 512;
  const size_t nSlow = (size_t)QN_ * 512;
  const size_t nW1 = (size_t)FF_ * 512, nW2 = (size_t)512 * FF_;
  const size_t nXbf = (size_t)M * HID_;
  const size_t poolElems = nIp + 2 * nSlow + 2 * nOut + nW1 + nW2 + nXbf + matN;

  size_t need = (size_t)M * HID_ * 4
              + ((size_t)M * QN_ + 2 * matN + poolElems) * 2;
  if (ws_size < need) return;

  float* cur   = (float*)d_ws;
  u16*   qkvbf = (u16*)(cur + (size_t)M * HID_);            // [M][1664] bf16
  u16*   attnSlot = qkvbf + (size_t)M * QN_;                // 2*matN u16
  u16*   MTg   = attnSlot;
  u16*   Ng    = MTg + matN;
  u16*   attnb = attnSlot;                                  // reuses MTg after p2
  u16*   CKg   = (u16*)out;
  u16*   U0Tg  = CKg + matN;
  u16*   tmpbf = (u16*)out;                                 // LN out; dead when CKg live
  u16*   hiddenb = qkvbf;                                   // FFN hidden (qkvbf+attn dead)

  u16* pool = attnSlot + 2 * matN;
  u16* ipwb   = pool;               pool += nIp;
  u16* slowb0 = pool;               pool += nSlow;
  u16* slowb1 = pool;               pool += nSlow;
  u16* outwb0 = pool;               pool += nOut;
  u16* outwb1 = pool;               pool += nOut;
  u16* w1b    = pool;               pool += nW1;
  u16* w2b    = pool;               pool += nW2;
  u16* Wsnap  = pool;               pool += matN;
  u16* xbf    = pool;

  dim3 blk(256);

  conv_w<<<(nIp + 255) / 256, blk, 0, stream>>>(ip_w, ipwb, nIp, nIp);
  conv_slow<<<QN_, blk, 0, stream>>>(fw_slow_w, slowb0);
  conv_slow<<<QN_, blk, 0, stream>>>(fw_slow_w + (size_t)SLOWSTRIDE, slowb1);
  conv_w<<<(nOut + 255) / 256, blk, 0, stream>>>(fw_out_w, outwb0, nOut, nOut);
  conv_w<<<(nOut + 255) / 256, blk, 0, stream>>>(fw_out_w + (size_t)512 * 512, outwb1, nOut, nOut);
  conv_w<<<(nW1 + 255) / 256, blk, 0, stream>>>(ff_w1, w1b, nW1, nW1);
  conv_w<<<(nW2 + 255) / 256, blk, 0, stream>>>(ff_w2, w2b, nW2, nW2);
  conv_x<<<M, 64, 0, stream>>>(x, xbf);

  gemm_bf<true, false, false, false, false, false><<<dim3(4, 128), blk, 0, stream>>>(
      xbf, ipwb, ip_b, nullptr, cur, M, HID_, HID_);

  for (int layer = 0; layer < 2; ++layer) {
    u16* slowb = layer ? slowb1 : slowb0;
    u16* outwb = layer ? outwb1 : outwb0;

    ln_bf<<<M, 64, 0, stream>>>(cur, fw_ln_g + layer * HID_, fw_ln_b + layer * HID_, tmpbf);
    gemm_bf<false, false, false, true, false, true><<<dim3(13, 128), blk, 0, stream>>>(
        tmpbf, slowb, nullptr, nullptr, qkvbf, M, QN_, HID_);
    delta_p1<<<64 * NCH_, 256, 0, stream>>>(qkvbf, MTg, Ng, CKg, U0Tg);
    delta_p2<<<64, 256, 0, stream>>>(MTg, Ng, Wsnap);
    delta_p3<<<64 * NCH_, 256, 0, stream>>>(qkvbf, Wsnap, CKg, U0Tg, attnb);
    if (layer == 0) {
      gemm_bf<false, false, true, false, false, false><<<dim3(4, 128), blk, 0, stream>>>(
          attnb, outwb, nullptr, cur, cur, M, HID_, HID_);
      ln_bf<<<M, 64, 0, stream>>>(cur, ff_ln_g, ff_ln_b, tmpbf);
      gemm_bf<true, true, false, true, false, false><<<dim3(16, 128), blk, 0, stream>>>(
          tmpbf, w1b, ff_b1, nullptr, hiddenb, M, FF_, HID_);
      gemm_bf<true, false, true, false, false, false><<<dim3(4, 128), blk, 0, stream>>>(
          hiddenb, w2b, ff_b2, cur, cur, M, HID_, FF_);
    } else {
      // final out-proj writes [B,S,512] directly (fused transpose)
      gemm_bf<false, false, true, false, true, false><<<dim3(4, 128), blk, 0, stream>>>(
          attnb, outwb, nullptr, cur, out, M, HID_, HID_);
    }
  }
}

// Round 11
// 543.931 us; speedup vs baseline: 1.3667x; 1.0231x over previous
//
#include <hip/hip_runtime.h>
#include <hip/hip_bf16.h>

#define B_    8
#define S_    2048
#define HID_  512
#define H_    8
#define D_    64
#define FF_   2048
#define QN_   1664   // padded qkvb width: q 512 | k 512 | v 512 | beta 8 (pad 128)
#define NCH_  32     // S/64 chunks
#define SLOWSTRIDE (1544 * 512)   // fw_slow_w per-layer stride (floats)

typedef unsigned short u16;
typedef __attribute__((ext_vector_type(8))) short short8;
typedef __attribute__((ext_vector_type(4))) float f32x4;

__device__ __forceinline__ u16 f2bf(float x) {           // RNE fp32->bf16
  unsigned u = __builtin_bit_cast(unsigned, x);
  unsigned r = (u + 0x7FFFu + ((u >> 16) & 1u)) >> 16;
  return (u16)r;
}
__device__ __forceinline__ float bf2f(u16 v) {
  return __builtin_bit_cast(float, (unsigned)v << 16);
}
__device__ __forceinline__ void gload16(const void* g, void* l) {
  __builtin_amdgcn_global_load_lds(
      (const __attribute__((address_space(1))) unsigned int*)g,
      (__attribute__((address_space(3))) unsigned int*)l, 16, 0, 0);
}

// 64x64x64 product C[r][c] = sum_k F[r][k]*G[c][k], bf16 LDS operands.
template<int FS, int GS>
__device__ __forceinline__ void prod64(const u16* __restrict__ F,
                                       const u16* __restrict__ G,
                                       int wrow0, int lane, f32x4 acc[4])
{
  short8 f0 = *(const short8*)&F[(wrow0 + (lane & 15)) * FS + ((lane >> 4) * 8)];
  short8 f1 = *(const short8*)&F[(wrow0 + (lane & 15)) * FS + 32 + ((lane >> 4) * 8)];
  #pragma unroll
  for (int c0 = 0; c0 < 4; ++c0) {
    short8 g0 = *(const short8*)&G[(c0 * 16 + (lane & 15)) * GS + ((lane >> 4) * 8)];
    short8 g1 = *(const short8*)&G[(c0 * 16 + (lane & 15)) * GS + 32 + ((lane >> 4) * 8)];
    acc[c0] = __builtin_amdgcn_mfma_f32_16x16x32_bf16(f0, g0, acc[c0], 0, 0, 0);
    acc[c0] = __builtin_amdgcn_mfma_f32_16x16x32_bf16(f1, g1, acc[c0], 0, 0, 0);
  }
}

// ---------------------------------------------------------------------------
// bf16 GEMM: BK=32 double-buffered global_load_lds staging, both-sides
// swizzle, 4-pass LDS-staged coalesced epilogue. (unchanged from R9)
// ---------------------------------------------------------------------------
template<bool BIAS, bool RELU, bool RES, bool OUTBF, bool TRANS, bool QKVB>
__global__ __launch_bounds__(256, 4) void gemm_bf(
    const u16* __restrict__ A, const u16* __restrict__ W,
    const float* __restrict__ bias, const float* __restrict__ res,
    void* __restrict__ Cout, int M, int N, int K)
{
  __shared__ __align__(16) u16 SH[16384];   // 32KB: [As0|Bs0|As1|Bs1]
  const int tid = threadIdx.x, lane = tid & 63, wv = tid >> 6;
  const int bm = blockIdx.y * 128, bn = blockIdx.x * 128;
  const int wr = wv >> 1, wc = wv & 1;
  const int row16 = lane & 15, kg = lane >> 4;
  const int srow = lane >> 2;
  const int ssoff = ((lane & 3) ^ (srow & 3)) * 16;

  f32x4 acc[4][4] = {};
  const int ktiles = K >> 5;

  auto STAGE = [&](int buf, int kt) {
    u16* As = &SH[buf * 8192];
    u16* Bs = &SH[buf * 8192 + 4096];
    #pragma unroll
    for (int i = 0; i < 2; ++i) {
      const int r = i * 64 + wv * 16;
      const char* ga = (const char*)(A + (size_t)(bm + r + srow) * K + (size_t)kt * 32) + ssoff;
      gload16(ga, &As[r * 32]);
      const char* gw = (const char*)(W + (size_t)(bn + r + srow) * K + (size_t)kt * 32) + ssoff;
      gload16(gw, &Bs[r * 32]);
    }
  };

  STAGE(0, 0);
  __syncthreads();
  int buf = 0;
  for (int kt = 0; kt < ktiles; ++kt) {
    if (kt + 1 < ktiles) STAGE(buf ^ 1, kt + 1);
    const u16* As = &SH[buf * 8192];
    const u16* Bs = &SH[buf * 8192 + 4096];
    short8 af[4], bf_[4];
    #pragma unroll
    for (int m = 0; m < 4; ++m) {
      const int lrow = wr * 64 + m * 16 + row16;
      af[m] = *(const short8*)&As[lrow * 32 + (kg ^ (lrow & 3)) * 8];
    }
    #pragma unroll
    for (int n = 0; n < 4; ++n) {
      const int lrow = wc * 64 + n * 16 + row16;
      bf_[n] = *(const short8*)&Bs[lrow * 32 + (kg ^ (lrow & 3)) * 8];
    }
    #pragma unroll
    for (int m = 0; m < 4; ++m)
      #pragma unroll
      for (int n = 0; n < 4; ++n)
        acc[m][n] = __builtin_amdgcn_mfma_f32_16x16x32_bf16(af[m], bf_[n], acc[m][n], 0, 0, 0);
    __syncthreads();
    buf ^= 1;
  }

  if (QKVB) {
    const int span0 = bn + wc * 64;
    #pragma unroll
    for (int m = 0; m < 4; ++m) {
      #pragma unroll
      for (int j = 0; j < 4; ++j) {
        if (span0 < 1024) {
          float v0 = acc[m][0][j], v1 = acc[m][1][j];
          float v2 = acc[m][2][j], v3 = acc[m][3][j];
          float mx = fmaxf(fmaxf(v0, v1), fmaxf(v2, v3));
          #pragma unroll
          for (int off = 1; off < 16; off <<= 1) mx = fmaxf(mx, __shfl_xor(mx, off));
          float e0 = __expf(v0 - mx), e1 = __expf(v1 - mx);
          float e2 = __expf(v2 - mx), e3 = __expf(v3 - mx);
          float s = (e0 + e1) + (e2 + e3);
          #pragma unroll
          for (int off = 1; off < 16; off <<= 1) s += __shfl_xor(s, off);
          float r = 1.f / s;
          acc[m][0][j] = e0 * r; acc[m][1][j] = e1 * r;
          acc[m][2][j] = e2 * r; acc[m][3][j] = e3 * r;
        } else if (span0 >= 1536) {
          #pragma unroll
          for (int n = 0; n < 4; ++n)
            acc[m][n][j] = 1.f / (1.f + __expf(-acc[m][n][j]));
        }
      }
    }
  }

  float* LD = (float*)SH;
  #pragma unroll
  for (int p = 0; p < 4; ++p) {
    if (p) __syncthreads();
    if (wr == (p >> 1)) {
      #pragma unroll
      for (int mm = 0; mm < 2; ++mm) {
        const int m = (p & 1) * 2 + mm;
        #pragma unroll
        for (int n = 0; n < 4; ++n)
          #pragma unroll
          for (int j = 0; j < 4; ++j)
            LD[(mm * 16 + kg * 4 + j) * 132 + wc * 64 + n * 16 + row16] = acc[m][n][j];
      }
    }
    __syncthreads();
    #pragma unroll
    for (int step = 0; step < 4; ++step) {
      int linear = step * 256 + tid;
      int row = linear >> 5, q = linear & 31;
      float4 v = *(const float4*)&LD[row * 132 + q * 4];
      const int grow = bm + p * 32 + row;
      const int gcol = bn + q * 4;
      if (BIAS) {
        float4 b4 = *(const float4*)&bias[gcol];
        v.x += b4.x; v.y += b4.y; v.z += b4.z; v.w += b4.w;
      }
      if (RES) {
        float4 r4 = *(const float4*)&res[(size_t)grow * N + gcol];
        v.x += r4.x; v.y += r4.y; v.z += r4.z; v.w += r4.w;
      }
      if (RELU) {
        v.x = fmaxf(v.x, 0.f); v.y = fmaxf(v.y, 0.f);
        v.z = fmaxf(v.z, 0.f); v.w = fmaxf(v.w, 0.f);
      }
      size_t gr = TRANS ? ((size_t)(grow & 7) * S_ + (grow >> 3)) : (size_t)grow;
      if (OUTBF) {
        uint2 pk;
        pk.x = (unsigned)f2bf(v.x) | ((unsigned)f2bf(v.y) << 16);
        pk.y = (unsigned)f2bf(v.z) | ((unsigned)f2bf(v.w) << 16);
        *(uint2*)&((u16*)Cout)[gr * N + gcol] = pk;
      } else {
        *(float4*)&((float*)Cout)[gr * N + gcol] = v;
      }
    }
  }
}

// ---------------------------------------------------------------------------
__global__ __launch_bounds__(256) void conv_w(const float* __restrict__ s,
                                              u16* __restrict__ d, int n, int npad)
{
  int i = blockIdx.x * 256 + threadIdx.x;
  if (i < npad) d[i] = (i < n) ? f2bf(s[i]) : (u16)0;
}

// slow_w reordered head-aligned: rows [q 512 | k 512 | v 512 | beta 8 | pad]
__global__ __launch_bounds__(256) void conv_slow(const float* __restrict__ s,
                                                 u16* __restrict__ d)
{
  int r = blockIdx.x;
  int src;
  if (r < 512)       src = (r >> 6) * 193 + (r & 63);
  else if (r < 1024) src = ((r - 512) >> 6) * 193 + 64 + (r & 63);
  else if (r < 1536) src = ((r - 1024) >> 6) * 193 + 128 + (r & 63);
  else if (r < 1544) src = (r - 1536) * 193 + 192;
  else               src = -1;
  for (int c = threadIdx.x; c < 512; c += 256)
    d[(size_t)r * 512 + c] = (src >= 0) ? f2bf(s[(size_t)src * 512 + c]) : (u16)0;
}

__global__ __launch_bounds__(64) void conv_x(const float* __restrict__ x,
                                             u16* __restrict__ xbf)
{
  size_t m = blockIdx.x;
  size_t s = m >> 3, b = m & 7;
  const float4* src = (const float4*)(x + (b * (size_t)S_ + s) * HID_);
  float4 v0 = src[threadIdx.x], v1 = src[64 + threadIdx.x];
  u16* dst = xbf + m * HID_;
  uint2 p0, p1;
  p0.x = (unsigned)f2bf(v0.x) | ((unsigned)f2bf(v0.y) << 16);
  p0.y = (unsigned)f2bf(v0.z) | ((unsigned)f2bf(v0.w) << 16);
  p1.x = (unsigned)f2bf(v1.x) | ((unsigned)f2bf(v1.y) << 16);
  p1.y = (unsigned)f2bf(v1.z) | ((unsigned)f2bf(v1.w) << 16);
  *(uint2*)&dst[threadIdx.x * 4] = p0;
  *(uint2*)&dst[256 + threadIdx.x * 4] = p1;
}

__global__ __launch_bounds__(64) void ln_bf(const float* __restrict__ x,
    const float* __restrict__ g, const float* __restrict__ bt,
    u16* __restrict__ o)
{
  size_t row = blockIdx.x;
  int lane = threadIdx.x;
  const float4* xr = (const float4*)(x + row * HID_);
  float4 v0 = xr[lane];
  float4 v1 = xr[64 + lane];
  float s  = v0.x + v0.y + v0.z + v0.w + v1.x + v1.y + v1.z + v1.w;
  float ss = v0.x*v0.x + v0.y*v0.y + v0.z*v0.z + v0.w*v0.w
           + v1.x*v1.x + v1.y*v1.y + v1.z*v1.z + v1.w*v1.w;
  #pragma unroll
  for (int off = 32; off; off >>= 1) {
    s  += __shfl_xor(s, off);
    ss += __shfl_xor(ss, off);
  }
  float mean = s * (1.f / HID_);
  float inv  = rsqrtf(ss * (1.f / HID_) - mean * mean + 1e-5f);
  const float4* gv = (const float4*)g;
  const float4* bv = (const float4*)bt;
  float4 g0 = gv[lane], g1 = gv[64 + lane];
  float4 b0 = bv[lane], b1 = bv[64 + lane];
  uint2 p0, p1;
  p0.x = (unsigned)f2bf((v0.x - mean) * inv * g0.x + b0.x)
       | ((unsigned)f2bf((v0.y - mean) * inv * g0.y + b0.y) << 16);
  p0.y = (unsigned)f2bf((v0.z - mean) * inv * g0.z + b0.z)
       | ((unsigned)f2bf((v0.w - mean) * inv * g0.w + b0.w) << 16);
  p1.x = (unsigned)f2bf((v1.x - mean) * inv * g1.x + b1.x)
       | ((unsigned)f2bf((v1.y - mean) * inv * g1.y + b1.y) << 16);
  p1.y = (unsigned)f2bf((v1.z - mean) * inv * g1.z + b1.z)
       | ((unsigned)f2bf((v1.w - mean) * inv * g1.w + b1.w) << 16);
  u16* ov = o + row * HID_;
  *(uint2*)&ov[lane * 4] = p0;
  *(uint2*)&ov[256 + lane * 4] = p1;
}

// ---------------------------------------------------------------------------
// Delta p1, register-resident solve edition.
//  LDS 41.7KB -> 3 blocks/CU. A stored bf16; per-wave solve rows live in
//  registers; cross-wave comm via 16-row bf16 stage buffers.
// ---------------------------------------------------------------------------
__global__ __launch_bounds__(256, 3) void delta_p1(const u16* __restrict__ qf,
                                                   u16* __restrict__ MTg,
                                                   u16* __restrict__ Ng,
                                                   u16* __restrict__ CKg,
                                                   u16* __restrict__ U0Tg)
{
  __shared__ __align__(16) u16 Kb[64 * 72];     // softmaxed K rows
  __shared__ __align__(16) u16 AmKT[64 * 72];   // A (bf16); post-solve: K^T
  __shared__ __align__(16) u16 stV[16 * 72];    // just-solved block rows (bf16)
  __shared__ __align__(16) u16 stK[16 * 72];
  __shared__ __align__(16) u16 CKTb[64 * 72];
  __shared__ __align__(16) u16 U0Tb[64 * 72];
  __shared__ float bet[64];

  const int id5 = blockIdx.x, bh = id5 >> 5;
  const int b = bh & 7, h = bh >> 3, t0 = (id5 & 31) * 64;
  const int tid = threadIdx.x, lane = tid & 63, wv = tid >> 6;
  const int wid = wv, wrow0 = wv * 16;
  const size_t mb = (size_t)id5 * 4096;

  #pragma unroll
  for (int p = 0; p < 2; ++p) {
    int linear = p * 256 + tid, row = linear >> 3, seg = linear & 7;
    uint4 k4 = *(const uint4*)&qf[((size_t)(t0 + row) * B_ + b) * QN_ + 512 + h * 64 + seg * 8];
    *(short8*)&Kb[row * 72 + seg * 8] = __builtin_bit_cast(short8, k4);
  }
  if (tid < 64) bet[tid] = bf2f(qf[((size_t)(t0 + tid) * B_ + b) * QN_ + 1536 + h]);
  __syncthreads();

  // A = beta ⊙ K K^T (MFMA) -> bf16
  {
    f32x4 a[4] = {};
    prod64<72, 72>(Kb, Kb, wrow0, lane, a);
    #pragma unroll
    for (int c0 = 0; c0 < 4; ++c0)
      #pragma unroll
      for (int j = 0; j < 4; ++j) {
        int row = wrow0 + (lane >> 4) * 4 + j, col = c0 * 16 + (lane & 15);
        AmKT[row * 72 + col] = f2bf(bet[row] * a[c0][j]);
      }
  }

  // per-wave solve state in registers: rows wrow0..+15, column = lane
  float uv[16], uk[16];
  #pragma unroll
  for (int i = 0; i < 16; ++i) {
    const int row = wrow0 + i;
    const float bt_ = bet[row];
    uv[i] = bt_ * bf2f(qf[((size_t)(t0 + row) * B_ + b) * QN_ + 1024 + h * 64 + lane]);
    uk[i] = bt_ * bf2f(Kb[row * 72 + lane]);
  }
  __syncthreads();   // A ready for all waves

  // blocked forward substitution, register-resident
  #pragma unroll 1
  for (int blk = 0; blk < 4; ++blk) {
    if (wid == blk) {
      const int r0 = blk * 16;
      #pragma unroll
      for (int jj = 0; jj < 15; ++jj) {
        #pragma unroll
        for (int t = jj + 1; t < 16; ++t) {
          float a = bf2f(AmKT[(r0 + t) * 72 + r0 + jj]);
          uv[t] = fmaf(-a, uv[jj], uv[t]);
          uk[t] = fmaf(-a, uk[jj], uk[t]);
        }
      }
      #pragma unroll
      for (int i = 0; i < 16; ++i) {
        stV[i * 72 + lane] = f2bf(uv[i]);
        stK[i * 72 + lane] = f2bf(uk[i]);
      }
    }
    __syncthreads();
    if (wid > blk) {
      const int r0 = blk * 16;
      #pragma unroll
      for (int jj = 0; jj < 16; ++jj) {
        float sv = bf2f(stV[jj * 72 + lane]);
        float sk = bf2f(stK[jj * 72 + lane]);
        #pragma unroll
        for (int i = 0; i < 16; ++i) {
          float a = bf2f(AmKT[(wrow0 + i) * 72 + r0 + jj]);
          uv[i] = fmaf(-a, sv, uv[i]);
          uk[i] = fmaf(-a, sk, uk[i]);
        }
      }
    }
    __syncthreads();
  }

  // outputs from registers: CK row-major (coalesced), CKT/U0T via LDS
  #pragma unroll
  for (int i = 0; i < 16; ++i) {
    const int row = wrow0 + i;
    u16 ck = f2bf(uk[i]), u0 = f2bf(uv[i]);
    CKg[mb + (size_t)row * 64 + lane] = ck;
    CKTb[lane * 72 + row] = ck;
    U0Tb[lane * 72 + row] = u0;
  }
  // K^T into AmKT (A dead)
  {
    const int prow = tid >> 2, pc0 = (tid & 3) * 16;
    #pragma unroll
    for (int i = 0; i < 16; ++i)
      AmKT[prow * 72 + pc0 + i] = Kb[(pc0 + i) * 72 + prow];
  }
  __syncthreads();

  // MT = K^T CK, N = U0^T K (MFMA); U0Tg coalesced copy
  {
    f32x4 am[4] = {}, an[4] = {};
    prod64<72, 72>(AmKT, CKTb, wrow0, lane, am);
    prod64<72, 72>(U0Tb, AmKT, wrow0, lane, an);
    #pragma unroll
    for (int c0 = 0; c0 < 4; ++c0)
      #pragma unroll
      for (int j = 0; j < 4; ++j) {
        int row = wrow0 + (lane >> 4) * 4 + j, col = c0 * 16 + (lane & 15);
        MTg[mb + (size_t)row * 64 + col] = f2bf(am[c0][j]);
        Ng[mb + (size_t)row * 64 + col]  = f2bf(an[c0][j]);
      }
    const int prow = tid >> 2, pc0 = (tid & 3) * 16;
    short8 a0 = *(const short8*)&U0Tb[prow * 72 + pc0];
    short8 a1 = *(const short8*)&U0Tb[prow * 72 + pc0 + 8];
    *(uint4*)&U0Tg[mb + prow * 64 + pc0]     = __builtin_bit_cast(uint4, a0);
    *(uint4*)&U0Tg[mb + prow * 64 + pc0 + 8] = __builtin_bit_cast(uint4, a1);
  }
}

__global__ __launch_bounds__(256, 1) void delta_p2(const u16* __restrict__ MTg,
                                                   const u16* __restrict__ Ng,
                                                   u16* __restrict__ Wsnap)
{
  __shared__ float Ws[64][65];
  __shared__ __align__(16) u16 Wbf[64 * 72];
  __shared__ __align__(16) u16 MTb[64 * 72];
  __shared__ __align__(16) u16 Nb[64 * 72];
  const int bh = blockIdx.x;
  const int tid = threadIdx.x, lane = tid & 63, wv = tid >> 6, wrow0 = wv * 16;
  const int prow = tid >> 2, pc0 = (tid & 3) * 16;

  for (int i = tid; i < 64 * 65; i += 256) (&Ws[0][0])[i] = 0.f;
  for (int i = tid; i < 64 * 72; i += 256) Wbf[i] = 0;
  __syncthreads();

  size_t base = (size_t)bh * NCH_ * 4096;
  uint4 rm0 = *(const uint4*)&MTg[base + prow * 64 + pc0];
  uint4 rm1 = *(const uint4*)&MTg[base + prow * 64 + pc0 + 8];
  uint4 rn0 = *(const uint4*)&Ng[base + prow * 64 + pc0];
  uint4 rn1 = *(const uint4*)&Ng[base + prow * 64 + pc0 + 8];

  for (int j = 0; j < NCH_; ++j) {
    *(short8*)&MTb[prow * 72 + pc0]     = __builtin_bit_cast(short8, rm0);
    *(short8*)&MTb[prow * 72 + pc0 + 8] = __builtin_bit_cast(short8, rm1);
    *(short8*)&Nb[prow * 72 + pc0]      = __builtin_bit_cast(short8, rn0);
    *(short8*)&Nb[prow * 72 + pc0 + 8]  = __builtin_bit_cast(short8, rn1);
    {
      size_t sb = base + (size_t)j * 4096;
      short8 w0 = *(const short8*)&Wbf[prow * 72 + pc0];
      short8 w1 = *(const short8*)&Wbf[prow * 72 + pc0 + 8];
      *(uint4*)&Wsnap[sb + prow * 64 + pc0]     = __builtin_bit_cast(uint4, w0);
      *(uint4*)&Wsnap[sb + prow * 64 + pc0 + 8] = __builtin_bit_cast(uint4, w1);
    }
    if (j + 1 < NCH_) {
      size_t nb2 = base + (size_t)(j + 1) * 4096;
      rm0 = *(const uint4*)&MTg[nb2 + prow * 64 + pc0];
      rm1 = *(const uint4*)&MTg[nb2 + prow * 64 + pc0 + 8];
      rn0 = *(const uint4*)&Ng[nb2 + prow * 64 + pc0];
      rn1 = *(const uint4*)&Ng[nb2 + prow * 64 + pc0 + 8];
    }
    __syncthreads();
    f32x4 a[4] = {};
    prod64<72, 72>(Wbf, MTb, wrow0, lane, a);
    #pragma unroll
    for (int c0 = 0; c0 < 4; ++c0)
      #pragma unroll
      for (int jj = 0; jj < 4; ++jj) {
        int row = wrow0 + (lane >> 4) * 4 + jj, col = c0 * 16 + (lane & 15);
        float w = Ws[row][col] + bf2f(Nb[row * 72 + col]) - a[c0][jj];
        Ws[row][col] = w;
        Wbf[row * 72 + col] = f2bf(w);
      }
    __syncthreads();
  }
}

__global__ __launch_bounds__(256, 2) void delta_p3(const u16* __restrict__ qf,
                                                   const u16* __restrict__ Wsnap,
                                                   const u16* __restrict__ CKg,
                                                   const u16* __restrict__ U0Tg,
                                                   u16* __restrict__ attnb)
{
  __shared__ __align__(16) u16 Qb[64 * 72];
  __shared__ __align__(16) u16 Kb[64 * 72];
  __shared__ __align__(16) u16 W0b[64 * 72];
  __shared__ __align__(16) u16 CKb[64 * 72];
  __shared__ __align__(16) u16 U0Tb[64 * 72];
  __shared__ __align__(16) u16 Gb[64 * 72];
  __shared__ __align__(16) u16 UTb[64 * 72];

  const int id5 = blockIdx.x, bh = id5 >> 5;
  const int b = bh & 7, h = bh >> 3, t0 = (id5 & 31) * 64;
  const int tid = threadIdx.x, lane = tid & 63, wv = tid >> 6, wrow0 = wv * 16;
  const int prow = tid >> 2, pc0 = (tid & 3) * 16;
  const size_t mb = (size_t)id5 * 4096;

  #pragma unroll
  for (int p = 0; p < 2; ++p) {
    int linear = p * 256 + tid, row = linear >> 3, seg = linear & 7;
    size_t gb = ((size_t)(t0 + row) * B_ + b) * QN_;
    uint4 q4 = *(const uint4*)&qf[gb + h * 64 + seg * 8];
    uint4 k4 = *(const uint4*)&qf[gb + 512 + h * 64 + seg * 8];
    uint4 w4 = *(const uint4*)&Wsnap[mb + (size_t)row * 64 + seg * 8];
    *(short8*)&Qb[row * 72 + seg * 8]  = __builtin_bit_cast(short8, q4);
    *(short8*)&Kb[row * 72 + seg * 8]  = __builtin_bit_cast(short8, k4);
    *(short8*)&W0b[row * 72 + seg * 8] = __builtin_bit_cast(short8, w4);
  }
  {
    uint4 c0v = *(const uint4*)&CKg[mb + prow * 64 + pc0];
    uint4 c1v = *(const uint4*)&CKg[mb + prow * 64 + pc0 + 8];
    uint4 u0v = *(const uint4*)&U0Tg[mb + prow * 64 + pc0];
    uint4 u1v = *(const uint4*)&U0Tg[mb + prow * 64 + pc0 + 8];
    *(short8*)&CKb[prow * 72 + pc0]      = __builtin_bit_cast(short8, c0v);
    *(short8*)&CKb[prow * 72 + pc0 + 8]  = __builtin_bit_cast(short8, c1v);
    *(short8*)&U0Tb[prow * 72 + pc0]     = __builtin_bit_cast(short8, u0v);
    *(short8*)&U0Tb[prow * 72 + pc0 + 8] = __builtin_bit_cast(short8, u1v);
  }
  __syncthreads();

  f32x4 ag[4] = {}, ac[4] = {}, ab[4] = {};
  prod64<72, 72>(Qb, Kb, wrow0, lane, ag);    // QK^T
  prod64<72, 72>(W0b, CKb, wrow0, lane, ac);  // (W0·CK^T)[d][t]
  prod64<72, 72>(Qb, W0b, wrow0, lane, ab);   // Q·W0^T

  #pragma unroll
  for (int c0 = 0; c0 < 4; ++c0)
    #pragma unroll
    for (int j = 0; j < 4; ++j) {
      int row = wrow0 + (lane >> 4) * 4 + j, col = c0 * 16 + (lane & 15);
      Gb[row * 72 + col]  = f2bf(col <= row ? ag[c0][j] : 0.f);
      UTb[row * 72 + col] = f2bf(bf2f(U0Tb[row * 72 + col]) - ac[c0][j]);
    }
  __syncthreads();

  prod64<72, 72>(Gb, UTb, wrow0, lane, ab);   // += G·U

  #pragma unroll
  for (int c0 = 0; c0 < 4; ++c0)
    #pragma unroll
    for (int j = 0; j < 4; ++j) {
      int row = wrow0 + (lane >> 4) * 4 + j, col = c0 * 16 + (lane & 15);
      attnb[((size_t)(t0 + row) * B_ + b) * HID_ + h * 64 + col] = f2bf(ab[c0][j]);
    }
}

// ---------------------------------------------------------------------------
extern "C" void kernel_launch(void* const* d_in, const int* in_sizes, int n_in,
                              void* d_out, int out_size, void* d_ws, size_t ws_size,
                              hipStream_t stream)
{
  const float* x        = (const float*)d_in[0];
  const float* ip_w     = (const float*)d_in[1];
  const float* ip_b     = (const float*)d_in[2];
  const float* fw_ln_g  = (const float*)d_in[3];
  const float* fw_ln_b  = (const float*)d_in[4];
  const float* fw_slow_w = (const float*)d_in[5];
  const float* fw_out_w  = (const float*)d_in[6];
  const float* ff_ln_g  = (const float*)d_in[7];
  const float* ff_ln_b  = (const float*)d_in[8];
  const float* ff_w1    = (const float*)d_in[9];
  const float* ff_b1    = (const float*)d_in[10];
  const float* ff_w2    = (const float*)d_in[11];
  const float* ff_b2    = (const float*)d_in[12];
  float* out = (float*)d_out;

  const int M = B_ * S_;  // 16384
  const size_t matN = (size_t)64 * NCH_ * 4096;   // 8.39M elems

  const size_t nIp = 512 * 512, nOut = 512 * 512;
  const size_t nSlow = (size_t)QN_ * 512;
  const size_t nW1 = (size_t)FF_ * 512, nW2 = (size_t)512 * FF_;
  const size_t nXbf = (size_t)M * HID_;
  const size_t poolElems = nIp + 2 * nSlow + 2 * nOut + nW1 + nW2 + nXbf + matN;

  size_t need = (size_t)M * HID_ * 4
              + ((size_t)M * QN_ + 2 * matN + poolElems) * 2;
  if (ws_size < need) return;

  float* cur   = (float*)d_ws;
  u16*   qkvbf = (u16*)(cur + (size_t)M * HID_);            // [M][1664] bf16
  u16*   attnSlot = qkvbf + (size_t)M * QN_;                // 2*matN u16
  u16*   MTg   = attnSlot;
  u16*   Ng    = MTg + matN;
  u16*   attnb = attnSlot;                                  // reuses MTg after p2
  u16*   CKg   = (u16*)out;
  u16*   U0Tg  = CKg + matN;
  u16*   tmpbf = (u16*)out;                                 // LN out; dead when CKg live
  u16*   hiddenb = qkvbf;                                   // FFN hidden

  u16* pool = attnSlot + 2 * matN;
  u16* ipwb   = pool;               pool += nIp;
  u16* slowb0 = pool;               pool += nSlow;
  u16* slowb1 = pool;               pool += nSlow;
  u16* outwb0 = pool;               pool += nOut;
  u16* outwb1 = pool;               pool += nOut;
  u16* w1b    = pool;               pool += nW1;
  u16* w2b    = pool;               pool += nW2;
  u16* Wsnap  = pool;               pool += matN;
  u16* xbf    = pool;

  dim3 blk(256);

  conv_w<<<(nIp + 255) / 256, blk, 0, stream>>>(ip_w, ipwb, nIp, nIp);
  conv_slow<<<QN_, blk, 0, stream>>>(fw_slow_w, slowb0);
  conv_slow<<<QN_, blk, 0, stream>>>(fw_slow_w + (size_t)SLOWSTRIDE, slowb1);
  conv_w<<<(nOut + 255) / 256, blk, 0, stream>>>(fw_out_w, outwb0, nOut, nOut);
  conv_w<<<(nOut + 255) / 256, blk, 0, stream>>>(fw_out_w + (size_t)512 * 512, outwb1, nOut, nOut);
  conv_w<<<(nW1 + 255) / 256, blk, 0, stream>>>(ff_w1, w1b, nW1, nW1);
  conv_w<<<(nW2 + 255) / 256, blk, 0, stream>>>(ff_w2, w2b, nW2, nW2);
  conv_x<<<M, 64, 0, stream>>>(x, xbf);

  gemm_bf<true, false, false, false, false, false><<<dim3(4, 128), blk, 0, stream>>>(
      xbf, ipwb, ip_b, nullptr, cur, M, HID_, HID_);

  for (int layer = 0; layer < 2; ++layer) {
    u16* slowb = layer ? slowb1 : slowb0;
    u16* outwb = layer ? outwb1 : outwb0;

    ln_bf<<<M, 64, 0, stream>>>(cur, fw_ln_g + layer * HID_, fw_ln_b + layer * HID_, tmpbf);
    gemm_bf<false, false, false, true, false, true><<<dim3(13, 128), blk, 0, stream>>>(
        tmpbf, slowb, nullptr, nullptr, qkvbf, M, QN_, HID_);
    delta_p1<<<64 * NCH_, 256, 0, stream>>>(qkvbf, MTg, Ng, CKg, U0Tg);
    delta_p2<<<64, 256, 0, stream>>>(MTg, Ng, Wsnap);
    delta_p3<<<64 * NCH_, 256, 0, stream>>>(qkvbf, Wsnap, CKg, U0Tg, attnb);
    if (layer == 0) {
      gemm_bf<false, false, true, false, false, false><<<dim3(4, 128), blk, 0, stream>>>(
          attnb, outwb, nullptr, cur, cur, M, HID_, HID_);
      ln_bf<<<M, 64, 0, stream>>>(cur, ff_ln_g, ff_ln_b, tmpbf);
      gemm_bf<true, true, false, true, false, false><<<dim3(16, 128), blk, 0, stream>>>(
          tmpbf, w1b, ff_b1, nullptr, hiddenb, M, FF_, HID_);
      gemm_bf<true, false, true, false, false, false><<<dim3(4, 128), blk, 0, stream>>>(
          hiddenb, w2b, ff_b2, cur, cur, M, HID_, FF_);
    } else {
      // final out-proj writes [B,S,512] directly (fused transpose)
      gemm_bf<false, false, true, false, true, false><<<dim3(4, 128), blk, 0, stream>>>(
          attnb, outwb, nullptr, cur, out, M, HID_, HID_);
    }
  }
}